// Round 1
// baseline (711.091 us; speedup 1.0000x reference)
//
#include <hip/hip_runtime.h>

typedef unsigned short u16;
typedef __bf16 bf16x8 __attribute__((ext_vector_type(8)));
typedef float f32x4 __attribute__((ext_vector_type(4)));

// ---------- numeric helpers (RNE f32<->bf16, matching XLA/ml_dtypes) ----------
__device__ __forceinline__ u16 f2bf(float f){
  unsigned int x = __float_as_uint(f);
  unsigned int r = (x + 0x7FFFu + ((x >> 16) & 1u)) >> 16;
  return (u16)r;
}
__device__ __forceinline__ float bf2f(u16 u){
  return __uint_as_float(((unsigned int)u) << 16);
}
__device__ __forceinline__ int compute_u(int qvlv){
  int mm = qvlv > 2 ? qvlv : 2;
  int u = (int)(5.0 * log((double)mm));   // FACTOR=5.0, python int() truncation
  if (u < 1) u = 1;
  if (u > 64) u = 64;
  return u;
}
__device__ __forceinline__ void gload_lds16(const void* g, void* l){
  __builtin_amdgcn_global_load_lds(
      (const __attribute__((address_space(1))) void*)g,
      (__attribute__((address_space(3))) void*)l, 16, 0, 0);
}

// ---------- K1: split f32 -> 3 bf16 levels (X for q/k/v, W for Wq/Wk/Wv) ----------
// level3 only kept for projection 0 (Q needs 6-term precision)
__global__ void expand_kernel(const float* __restrict__ xq, const float* __restrict__ xk,
                              const float* __restrict__ xv,
                              const float* __restrict__ wq, const float* __restrict__ wk,
                              const float* __restrict__ wv,
                              u16* __restrict__ X1, u16* __restrict__ X2, u16* __restrict__ X3,
                              u16* __restrict__ W1, u16* __restrict__ W2, u16* __restrict__ W3)
{
  size_t g = (size_t)blockIdx.x * 256 + threadIdx.x;  // one group = 4 floats
  const float* src; u16 *d1, *d2, *d3;
  if (g < 3145728ull) {                 // X part: 3 * 4194304 / 4
    int p = (int)(g >> 20);
    size_t e = (g & 1048575ull) * 4;
    src = (p == 0 ? xq : (p == 1 ? xk : xv)) + e;
    size_t o = (size_t)p * 4194304ull + e;
    d1 = X1 + o; d2 = X2 + o; d3 = (p == 0) ? (X3 + e) : (u16*)0;
  } else {                              // W part: 3 * 1048576 / 4
    size_t wg = g - 3145728ull;
    int p = (int)(wg >> 18);
    size_t e = (wg & 262143ull) * 4;
    src = (p == 0 ? wq : (p == 1 ? wk : wv)) + e;
    size_t o = (size_t)p * 1048576ull + e;
    d1 = W1 + o; d2 = W2 + o; d3 = (p == 0) ? (W3 + e) : (u16*)0;
  }
  float4 x = *reinterpret_cast<const float4*>(src);
  float xs[4] = {x.x, x.y, x.z, x.w};
  u16 h1[4], h2[4], h3[4];
#pragma unroll
  for (int i = 0; i < 4; ++i){
    float v = xs[i];
    u16 a = f2bf(v);  float r1 = v  - bf2f(a);
    u16 b = f2bf(r1); float r2 = r1 - bf2f(b);
    u16 c = f2bf(r2);
    h1[i] = a; h2[i] = b; h3[i] = c;
  }
  *reinterpret_cast<ushort4*>(d1) = make_ushort4(h1[0], h1[1], h1[2], h1[3]);
  *reinterpret_cast<ushort4*>(d2) = make_ushort4(h2[0], h2[1], h2[2], h2[3]);
  if (d3) *reinterpret_cast<ushort4*>(d3) = make_ushort4(h3[0], h3[1], h3[2], h3[3]);
}

// ---------- K2: WoT[j][d] = Wo[d][j] ----------
__global__ void wot_kernel(const float* __restrict__ Wo, float* __restrict__ WoT){
  __shared__ float tile[32][33];
  int tx = threadIdx.x, ty = threadIdx.y;   // 32 x 8
  int bx = blockIdx.x * 32, by = blockIdx.y * 32;
#pragma unroll
  for (int r = 0; r < 4; ++r)
    tile[ty + r*8][tx] = Wo[(size_t)(by + ty + r*8) * 1024 + bx + tx];
  __syncthreads();
#pragma unroll
  for (int r = 0; r < 4; ++r)
    WoT[(size_t)(bx + ty + r*8) * 1024 + by + tx] = tile[tx][ty + r*8];
}

// ---------- K3: split-precision bf16 MFMA GEMM  C = X @ W^T + bias ----------
// z=0: Q, 6 terms (h1h1,h1h2,h2h1,h2h2,h1h3,h3h1) ~= f32 exact
// z=1,2: K,V, 3 terms (h1h1,h1h2,h2h1)
// 128x128 tile, BK=32, 4 waves, 16x16x32 bf16 MFMA (m97 structure)
__global__ __launch_bounds__(256, 3) void gemm_proj(
    const u16* __restrict__ X1, const u16* __restrict__ X2, const u16* __restrict__ X3,
    const u16* __restrict__ W1, const u16* __restrict__ W2, const u16* __restrict__ W3,
    const float* __restrict__ bq, const float* __restrict__ bk, const float* __restrict__ bv,
    float* __restrict__ PROJ)
{
  int z = blockIdx.z;
  const u16* Xl0 = X1 + (size_t)z * 4194304;
  const u16* Xl1 = X2 + (size_t)z * 4194304;
  const u16* Xl2 = X3;                       // only valid/used when z==0
  const u16* Wl0 = W1 + (size_t)z * 1048576;
  const u16* Wl1 = W2 + (size_t)z * 1048576;
  const u16* Wl2 = W3;
  const float* bias = (z == 0) ? bq : (z == 1 ? bk : bv);
  float* C = PROJ + (size_t)z * 4194304;
  int nt = (z == 0) ? 6 : 3;
  const int aPack = 2128;  // levels {0,0,1,1,0,2} packed 2b
  const int bPack = 580;   // levels {0,1,0,1,2,0}

  __shared__ __align__(16) u16 As[128 * 32];
  __shared__ __align__(16) u16 Bs[128 * 32];
  int t = threadIdx.x;
  int wave = t >> 6, lane = t & 63;
  int wm = wave >> 1, wn = wave & 1;
  f32x4 acc[4][4] = {};
  int KT = nt * 32;
  for (int kt = 0; kt < KT; ++kt){
    int term = kt >> 5;
    int pk = (kt & 31) * 32;
    int alv = (aPack >> (2 * term)) & 3;
    int blv = (bPack >> (2 * term)) & 3;
    const u16* Ab = (alv == 0) ? Xl0 : (alv == 1 ? Xl1 : Xl2);
    const u16* Bb = (blv == 0) ? Wl0 : (blv == 1 ? Wl1 : Wl2);
#pragma unroll
    for (int i = 0; i < 2; ++i){
      int c = i * 256 + t;
      const u16* src = Ab + (size_t)(blockIdx.y * 128 + (c >> 2)) * 1024 + pk + (c & 3) * 8;
      gload_lds16(src, &As[(i * 256 + wave * 64) * 8]);
    }
#pragma unroll
    for (int i = 0; i < 2; ++i){
      int c = i * 256 + t;
      const u16* src = Bb + (size_t)(blockIdx.x * 128 + (c >> 2)) * 1024 + pk + (c & 3) * 8;
      gload_lds16(src, &Bs[(i * 256 + wave * 64) * 8]);
    }
    __syncthreads();
    bf16x8 af[4], bg[4];
#pragma unroll
    for (int m = 0; m < 4; ++m){
      int r = wm * 64 + m * 16 + (lane & 15);
      af[m] = *reinterpret_cast<const bf16x8*>(&As[r * 32 + (lane >> 4) * 8]);
    }
#pragma unroll
    for (int n = 0; n < 4; ++n){
      int r = wn * 64 + n * 16 + (lane & 15);
      bg[n] = *reinterpret_cast<const bf16x8*>(&Bs[r * 32 + (lane >> 4) * 8]);
    }
#pragma unroll
    for (int m = 0; m < 4; ++m)
#pragma unroll
      for (int n = 0; n < 4; ++n)
        acc[m][n] = __builtin_amdgcn_mfma_f32_16x16x32_bf16(af[m], bg[n], acc[m][n], 0, 0, 0);
    __syncthreads();
  }
  // epilogue: C/D layout col = lane&15, row = (lane>>4)*4 + j  (m89-verified)
#pragma unroll
  for (int m = 0; m < 4; ++m){
    int row0 = blockIdx.y * 128 + wm * 64 + m * 16 + (lane >> 4) * 4;
#pragma unroll
    for (int n = 0; n < 4; ++n){
      int col = blockIdx.x * 128 + wn * 64 + n * 16 + (lane & 15);
      float bb = bias[col];
#pragma unroll
      for (int j = 0; j < 4; ++j)
        C[(size_t)(row0 + j) * 1024 + col] = acc[m][n][j] + bb;
    }
  }
}

// ---------- K4: q_norm[b,h,l] = sum_d Q[b,l,h*64+d]^2 ----------
__global__ void qnorm_kernel(const float* __restrict__ PROJ, float* __restrict__ qn){
  int g = blockIdx.x * 256 + threadIdx.x;   // 65536
  int b = g >> 15, rem = g & 32767, h = rem >> 11, l = rem & 2047;
  const float* q = PROJ + (size_t)(b * 2048 + l) * 1024 + h * 64;
  float s = 0.f;
#pragma unroll 8
  for (int d = 0; d < 64; ++d){ float x = q[d]; s += x * x; }
  qn[(size_t)(b * 16 + h) * 2048 + l] = s;
}

// ---------- K5: iterative top-u argmax per (b,h); tie -> lower index ----------
__global__ void topk_kernel(const float* __restrict__ qn, int* __restrict__ topk,
                            unsigned char* __restrict__ seli, unsigned int* __restrict__ hmask,
                            const int* __restrict__ qvlp){
  int bh = blockIdx.x; int b = bh >> 4, h = bh & 15;
  int u = compute_u(qvlp[0]);
  __shared__ float v[2048];
  __shared__ float rv[256];
  __shared__ int ri[256];
  int t = threadIdx.x;
  for (int j = t; j < 2048; j += 256) v[j] = qn[(size_t)bh * 2048 + j];
  __syncthreads();
  for (int it = 0; it < u; ++it){
    float bvv = -3.4e38f; int bi = 2048;
    for (int j = t; j < 2048; j += 256){ float x = v[j]; if (x > bvv){ bvv = x; bi = j; } }
    rv[t] = bvv; ri[t] = bi;
    __syncthreads();
    for (int s = 128; s > 0; s >>= 1){
      if (t < s){
        if (rv[t+s] > rv[t] || (rv[t+s] == rv[t] && ri[t+s] < ri[t])){ rv[t] = rv[t+s]; ri[t] = ri[t+s]; }
      }
      __syncthreads();
    }
    if (t == 0){
      int idx = ri[0];
      topk[bh * 64 + it] = idx;
      seli[(size_t)bh * 2048 + idx] = (unsigned char)it;
      atomicOr(&hmask[b * 2048 + idx], 1u << h);
      v[idx] = -3.4e38f;
    }
    __syncthreads();
  }
}

// ---------- K6: scores for selected rows; bf16 round + bf16 mask add ----------
__global__ void scores_kernel(const float* __restrict__ PROJ, const int* __restrict__ topk,
                              const float* __restrict__ maskp, u16* __restrict__ sc,
                              const int* __restrict__ qvlp, const int* __restrict__ kvlp){
  int bh = blockIdx.y; int b = bh >> 4, h = bh & 15;
  int kvlv = kvlp[0]; if (kvlv > 2048) kvlv = 2048; if (kvlv < 0) kvlv = 0;
  int u = compute_u(qvlp[0]);
  int k0 = blockIdx.x * 128;
  if (k0 >= kvlv) return;
  int kcnt = kvlv - k0; if (kcnt > 128) kcnt = 128;
  int t = threadIdx.x;
  __shared__ int idx_l[64];
  __shared__ float qld[64 * 64];
  __shared__ float kld[128 * 65];
  const float* Q = PROJ;
  const float* K = PROJ + 4194304;
  if (t < u) idx_l[t] = topk[bh * 64 + t];
  __syncthreads();
  for (int e = t; e < u * 64; e += 256){
    int i = e >> 6, d = e & 63;
    qld[e] = Q[(size_t)(b * 2048 + idx_l[i]) * 1024 + h * 64 + d];
  }
  for (int e = t; e < 128 * 64; e += 256){
    int kk = e >> 6, d = e & 63;
    float vv = (kk < kcnt) ? K[(size_t)(b * 2048 + k0 + kk) * 1024 + h * 64 + d] : 0.f;
    kld[kk * 65 + d] = vv;
  }
  __syncthreads();
  for (int e = t; e < u * 128; e += 256){
    int i = e >> 7, kk = e & 127;
    if (kk >= kcnt) continue;
    const float* qr = &qld[i * 64];
    const float* kr = &kld[kk * 65];
    float s = 0.f;
#pragma unroll 8
    for (int d = 0; d < 64; ++d) s += qr[d] * kr[d];
    s *= 0.125f;                          // / sqrt(64)
    int l = idx_l[i]; int k = k0 + kk;
    u16 xb = f2bf(s);                     // scores.astype(bf16)
    u16 mb = f2bf(maskp[(size_t)l * 2048 + k]);   // attn_mask.astype(bf16) (kpm=0 here)
    u16 xm = f2bf(bf2f(xb) + bf2f(mb));   // bf16 add
    sc[(size_t)(bh * 64 + i) * 2048 + k] = xm;
  }
}

// ---------- K7: exact bf16 softmax emulation; p written in place ----------
__global__ void softmax_kernel(u16* __restrict__ sc, const int* __restrict__ qvlp,
                               const int* __restrict__ kvlp){
  int bh = blockIdx.y, i = blockIdx.x;
  int u = compute_u(qvlp[0]);
  if (i >= u) return;
  int kvlv = kvlp[0]; if (kvlv > 2048) kvlv = 2048; if (kvlv < 0) kvlv = 0;
  u16* row = sc + (size_t)(bh * 64 + i) * 2048;
  int t = threadIdx.x;
  float x[8];
  float lm = -3.4e38f;
#pragma unroll
  for (int j = 0; j < 8; ++j){
    int k = t + j * 256;
    x[j] = (k < kvlv) ? bf2f(row[k]) : -3.4e38f;
    lm = fmaxf(lm, x[j]);
  }
  __shared__ float red[256];
  red[t] = lm; __syncthreads();
  for (int s = 128; s > 0; s >>= 1){ if (t < s) red[t] = fmaxf(red[t], red[t+s]); __syncthreads(); }
  float m = red[0];
  __syncthreads();
  float e[8]; float ls = 0.f;
#pragma unroll
  for (int j = 0; j < 8; ++j){
    int k = t + j * 256;
    if (k < kvlv){
      u16 ub = f2bf(x[j] - m);            // bf16 subtract
      u16 eb = f2bf(expf(bf2f(ub)));      // bf16 exp
      e[j] = bf2f(eb);
      ls += e[j];
    } else e[j] = 0.f;
  }
  red[t] = ls; __syncthreads();
  for (int s = 128; s > 0; s >>= 1){ if (t < s) red[t] += red[t+s]; __syncthreads(); }
  float S = red[0];                       // f32 accumulation (jnp.sum upcast)
  float Sb = bf2f(f2bf(S));               // downcast back to bf16
#pragma unroll
  for (int j = 0; j < 8; ++j){
    int k = t + j * 256;
    if (k < 2048) row[k] = (k < kvlv) ? f2bf(e[j] / Sb) : (u16)0;   // bf16 divide
  }
}

// ---------- K8: context = P @ V for selected rows (4 rows share V reads) ----------
__global__ void pv_kernel(const float* __restrict__ PROJ, const u16* __restrict__ probs,
                          float* __restrict__ ctx, const int* __restrict__ qvlp,
                          const int* __restrict__ kvlp){
  int bh = blockIdx.y;
  int u = compute_u(qvlp[0]);
  int i0 = blockIdx.x * 4;
  if (i0 >= u) return;
  int nr = u - i0; if (nr > 4) nr = 4;
  int b = bh >> 4, h = bh & 15;
  int kvlv = kvlp[0]; if (kvlv > 2048) kvlv = 2048; if (kvlv < 0) kvlv = 0;
  const float* V = PROJ + 2 * 4194304;
  int t = threadIdx.x, d = t & 63, g = t >> 6;
  const u16* pr = probs + (size_t)(bh * 64 + i0) * 2048;
  float acc[4] = {0.f, 0.f, 0.f, 0.f};
  for (int k = g; k < kvlv; k += 4){
    float vv = V[(size_t)(b * 2048 + k) * 1024 + h * 64 + d];
#pragma unroll
    for (int r = 0; r < 4; ++r)
      if (r < nr) acc[r] += bf2f(pr[(size_t)r * 2048 + k]) * vv;
  }
  __shared__ float red[4 * 256];
#pragma unroll
  for (int r = 0; r < 4; ++r) red[r * 256 + t] = acc[r];
  __syncthreads();
  if (t < 64){
#pragma unroll
    for (int r = 0; r < 4; ++r){
      if (r < nr){
        float s = red[r*256 + t] + red[r*256 + t + 64] + red[r*256 + t + 128] + red[r*256 + t + 192];
        ctx[(size_t)(bh * 64 + i0 + r) * 64 + d] = s;
      }
    }
  }
}

// ---------- K9: sparse output projection; unselected rows = bo ----------
__global__ void outproj_kernel(const float* __restrict__ ctx, const float* __restrict__ WoT,
                               const float* __restrict__ bo, const unsigned int* __restrict__ hmask,
                               const unsigned char* __restrict__ seli, float* __restrict__ out){
  int row = blockIdx.x;                 // b*2048 + l
  int b = row >> 11, l = row & 2047;
  int t = threadIdx.x;
  float acc[4];
#pragma unroll
  for (int r = 0; r < 4; ++r) acc[r] = bo[t + r * 256];
  unsigned int m = hmask[row];
  __shared__ float clds[64];
  while (m){
    int h = __ffs(m) - 1; m &= (m - 1);
    int i = (int)seli[(size_t)(b * 16 + h) * 2048 + l];
    __syncthreads();
    if (t < 64) clds[t] = ctx[(size_t)((b * 16 + h) * 64 + i) * 64 + t];
    __syncthreads();
    for (int j = 0; j < 64; ++j){
      float c = clds[j];
      const float* wrow = &WoT[(size_t)(h * 64 + j) * 1024];
#pragma unroll
      for (int r = 0; r < 4; ++r) acc[r] += c * wrow[t + r * 256];
    }
  }
  float* orow = out + (size_t)row * 1024;
#pragma unroll
  for (int r = 0; r < 4; ++r) orow[t + r * 256] = acc[r];
}

__global__ void fail_fill(float* o, int n){
  int i = blockIdx.x * 256 + threadIdx.x;
  if (i < n) o[i] = 12345.0f;
}

// ---------------------------------------------------------------------------
extern "C" void kernel_launch(void* const* d_in, const int* in_sizes, int n_in,
                              void* d_out, int out_size, void* d_ws, size_t ws_size,
                              hipStream_t stream)
{
  const float* query = (const float*)d_in[0];
  const float* key   = (const float*)d_in[1];
  const float* value = (const float*)d_in[2];
  const float* maskp = (const float*)d_in[3];
  const float* Wq = (const float*)d_in[4];
  const float* bq = (const float*)d_in[5];
  const float* Wk = (const float*)d_in[6];
  const float* bk = (const float*)d_in[7];
  const float* Wv = (const float*)d_in[8];
  const float* bv = (const float*)d_in[9];
  const float* Wo = (const float*)d_in[10];
  const float* bo = (const float*)d_in[11];
  const int* qvl = (const int*)d_in[12];
  const int* kvl = (const int*)d_in[13];
  float* out = (float*)d_out;

  char* ws = (char*)d_ws;
  size_t off = 0;
  auto alloc = [&](size_t bytes) -> void* {
    void* p = ws + off;
    off = (off + bytes + 255) & ~(size_t)255;
    return p;
  };
  u16* X1 = (u16*)alloc(3ull * 4194304 * 2);
  u16* X2 = (u16*)alloc(3ull * 4194304 * 2);
  u16* X3 = (u16*)alloc(1ull * 4194304 * 2);
  u16* W1 = (u16*)alloc(3ull * 1048576 * 2);
  u16* W2 = (u16*)alloc(3ull * 1048576 * 2);
  u16* W3 = (u16*)alloc(1ull * 1048576 * 2);
  float* PROJ = (float*)alloc(3ull * 4194304 * 4);
  float* WOT  = (float*)alloc(4194304ull);
  float* QN   = (float*)alloc(2ull * 16 * 2048 * 4);
  int*   TOPK = (int*)alloc(2ull * 16 * 64 * 4);
  unsigned char* SELI = (unsigned char*)alloc(2ull * 16 * 2048);
  unsigned int* HMASK = (unsigned int*)alloc(2ull * 2048 * 4);
  u16*   SC   = (u16*)alloc(2048ull * 2048 * 2);
  float* CTX  = (float*)alloc(2048ull * 64 * 4);

  if (ws_size < off){
    fail_fill<<<(out_size + 255) / 256, 256, 0, stream>>>(out, out_size);
    return;
  }

  hipMemsetAsync(SELI, 0xFF, 2ull * 16 * 2048, stream);
  hipMemsetAsync(HMASK, 0, 2ull * 2048 * 4, stream);

  expand_kernel<<<15360, 256, 0, stream>>>(query, key, value, Wq, Wk, Wv,
                                           X1, X2, X3, W1, W2, W3);
  wot_kernel<<<dim3(32, 32), dim3(32, 8), 0, stream>>>(Wo, WOT);
  gemm_proj<<<dim3(8, 32, 3), 256, 0, stream>>>(X1, X2, X3, W1, W2, W3, bq, bk, bv, PROJ);
  qnorm_kernel<<<256, 256, 0, stream>>>(PROJ, QN);
  topk_kernel<<<32, 256, 0, stream>>>(QN, TOPK, SELI, HMASK, qvl);
  scores_kernel<<<dim3(16, 32), 256, 0, stream>>>(PROJ, TOPK, maskp, SC, qvl, kvl);
  softmax_kernel<<<dim3(64, 32), 256, 0, stream>>>(SC, qvl, kvl);
  pv_kernel<<<dim3(16, 32), 256, 0, stream>>>(PROJ, SC, CTX, qvl, kvl);
  outproj_kernel<<<4096, 256, 0, stream>>>(CTX, WOT, bo, HMASK, SELI, out);
}

// Round 2
// 613.699 us; speedup vs baseline: 1.1587x; 1.1587x over previous
//
#include <hip/hip_runtime.h>

typedef unsigned short u16;
typedef __bf16 bf16x8 __attribute__((ext_vector_type(8)));
typedef float f32x4 __attribute__((ext_vector_type(4)));

// ---------- numeric helpers (RNE f32<->bf16, matching XLA/ml_dtypes) ----------
__device__ __forceinline__ u16 f2bf(float f){
  unsigned int x = __float_as_uint(f);
  unsigned int r = (x + 0x7FFFu + ((x >> 16) & 1u)) >> 16;
  return (u16)r;
}
__device__ __forceinline__ float bf2f(u16 u){
  return __uint_as_float(((unsigned int)u) << 16);
}
__device__ __forceinline__ int compute_u(int qvlv){
  int mm = qvlv > 2 ? qvlv : 2;
  int u = (int)(5.0 * log((double)mm));   // FACTOR=5.0, python int() truncation
  if (u < 1) u = 1;
  if (u > 64) u = 64;
  return u;
}
__device__ __forceinline__ void gload_lds16(const void* g, void* l){
  __builtin_amdgcn_global_load_lds(
      (const __attribute__((address_space(1))) void*)g,
      (__attribute__((address_space(3))) void*)l, 16, 0, 0);
}

// ---------- K1: split f32 -> 3 bf16 levels (X for q/k/v, W for Wq/Wk/Wv) ----------
__global__ void expand_kernel(const float* __restrict__ xq, const float* __restrict__ xk,
                              const float* __restrict__ xv,
                              const float* __restrict__ wq, const float* __restrict__ wk,
                              const float* __restrict__ wv,
                              u16* __restrict__ X1, u16* __restrict__ X2, u16* __restrict__ X3,
                              u16* __restrict__ W1, u16* __restrict__ W2, u16* __restrict__ W3)
{
  size_t g = (size_t)blockIdx.x * 256 + threadIdx.x;  // one group = 4 floats
  const float* src; u16 *d1, *d2, *d3;
  if (g < 3145728ull) {                 // X part: 3 * 4194304 / 4
    int p = (int)(g >> 20);
    size_t e = (g & 1048575ull) * 4;
    src = (p == 0 ? xq : (p == 1 ? xk : xv)) + e;
    size_t o = (size_t)p * 4194304ull + e;
    d1 = X1 + o; d2 = X2 + o; d3 = (p == 0) ? (X3 + e) : (u16*)0;
  } else {                              // W part: 3 * 1048576 / 4
    size_t wg = g - 3145728ull;
    int p = (int)(wg >> 18);
    size_t e = (wg & 262143ull) * 4;
    src = (p == 0 ? wq : (p == 1 ? wk : wv)) + e;
    size_t o = (size_t)p * 1048576ull + e;
    d1 = W1 + o; d2 = W2 + o; d3 = (p == 0) ? (W3 + e) : (u16*)0;
  }
  float4 x = *reinterpret_cast<const float4*>(src);
  float xs[4] = {x.x, x.y, x.z, x.w};
  u16 h1[4], h2[4], h3[4];
#pragma unroll
  for (int i = 0; i < 4; ++i){
    float v = xs[i];
    u16 a = f2bf(v);  float r1 = v  - bf2f(a);
    u16 b = f2bf(r1); float r2 = r1 - bf2f(b);
    u16 c = f2bf(r2);
    h1[i] = a; h2[i] = b; h3[i] = c;
  }
  *reinterpret_cast<ushort4*>(d1) = make_ushort4(h1[0], h1[1], h1[2], h1[3]);
  *reinterpret_cast<ushort4*>(d2) = make_ushort4(h2[0], h2[1], h2[2], h2[3]);
  if (d3) *reinterpret_cast<ushort4*>(d3) = make_ushort4(h3[0], h3[1], h3[2], h3[3]);
}

// ---------- K2: WoT[j][d] = Wo[d][j] ----------
__global__ void wot_kernel(const float* __restrict__ Wo, float* __restrict__ WoT){
  __shared__ float tile[32][33];
  int tx = threadIdx.x, ty = threadIdx.y;   // 32 x 8
  int bx = blockIdx.x * 32, by = blockIdx.y * 32;
#pragma unroll
  for (int r = 0; r < 4; ++r)
    tile[ty + r*8][tx] = Wo[(size_t)(by + ty + r*8) * 1024 + bx + tx];
  __syncthreads();
#pragma unroll
  for (int r = 0; r < 4; ++r)
    WoT[(size_t)(bx + ty + r*8) * 1024 + by + tx] = tile[tx][ty + r*8];
}

// ---------- K3: split-precision bf16 MFMA GEMM  C = X @ W^T + bias ----------
__global__ __launch_bounds__(256, 3) void gemm_proj(
    const u16* __restrict__ X1, const u16* __restrict__ X2, const u16* __restrict__ X3,
    const u16* __restrict__ W1, const u16* __restrict__ W2, const u16* __restrict__ W3,
    const float* __restrict__ bq, const float* __restrict__ bk, const float* __restrict__ bv,
    float* __restrict__ PROJ)
{
  int z = blockIdx.z;
  const u16* Xl0 = X1 + (size_t)z * 4194304;
  const u16* Xl1 = X2 + (size_t)z * 4194304;
  const u16* Xl2 = X3;                       // only valid/used when z==0
  const u16* Wl0 = W1 + (size_t)z * 1048576;
  const u16* Wl1 = W2 + (size_t)z * 1048576;
  const u16* Wl2 = W3;
  const float* bias = (z == 0) ? bq : (z == 1 ? bk : bv);
  float* C = PROJ + (size_t)z * 4194304;
  int nt = (z == 0) ? 6 : 3;
  const int aPack = 2128;  // levels {0,0,1,1,0,2} packed 2b
  const int bPack = 580;   // levels {0,1,0,1,2,0}

  __shared__ __align__(16) u16 As[128 * 32];
  __shared__ __align__(16) u16 Bs[128 * 32];
  int t = threadIdx.x;
  int wave = t >> 6, lane = t & 63;
  int wm = wave >> 1, wn = wave & 1;
  f32x4 acc[4][4] = {};
  int KT = nt * 32;
  for (int kt = 0; kt < KT; ++kt){
    int term = kt >> 5;
    int pk = (kt & 31) * 32;
    int alv = (aPack >> (2 * term)) & 3;
    int blv = (bPack >> (2 * term)) & 3;
    const u16* Ab = (alv == 0) ? Xl0 : (alv == 1 ? Xl1 : Xl2);
    const u16* Bb = (blv == 0) ? Wl0 : (blv == 1 ? Wl1 : Wl2);
#pragma unroll
    for (int i = 0; i < 2; ++i){
      int c = i * 256 + t;
      const u16* src = Ab + (size_t)(blockIdx.y * 128 + (c >> 2)) * 1024 + pk + (c & 3) * 8;
      gload_lds16(src, &As[(i * 256 + wave * 64) * 8]);
    }
#pragma unroll
    for (int i = 0; i < 2; ++i){
      int c = i * 256 + t;
      const u16* src = Bb + (size_t)(blockIdx.x * 128 + (c >> 2)) * 1024 + pk + (c & 3) * 8;
      gload_lds16(src, &Bs[(i * 256 + wave * 64) * 8]);
    }
    __syncthreads();
    bf16x8 af[4], bg[4];
#pragma unroll
    for (int m = 0; m < 4; ++m){
      int r = wm * 64 + m * 16 + (lane & 15);
      af[m] = *reinterpret_cast<const bf16x8*>(&As[r * 32 + (lane >> 4) * 8]);
    }
#pragma unroll
    for (int n = 0; n < 4; ++n){
      int r = wn * 64 + n * 16 + (lane & 15);
      bg[n] = *reinterpret_cast<const bf16x8*>(&Bs[r * 32 + (lane >> 4) * 8]);
    }
#pragma unroll
    for (int m = 0; m < 4; ++m)
#pragma unroll
      for (int n = 0; n < 4; ++n)
        acc[m][n] = __builtin_amdgcn_mfma_f32_16x16x32_bf16(af[m], bg[n], acc[m][n], 0, 0, 0);
    __syncthreads();
  }
#pragma unroll
  for (int m = 0; m < 4; ++m){
    int row0 = blockIdx.y * 128 + wm * 64 + m * 16 + (lane >> 4) * 4;
#pragma unroll
    for (int n = 0; n < 4; ++n){
      int col = blockIdx.x * 128 + wn * 64 + n * 16 + (lane & 15);
      float bb = bias[col];
#pragma unroll
      for (int j = 0; j < 4; ++j)
        C[(size_t)(row0 + j) * 1024 + col] = acc[m][n][j] + bb;
    }
  }
}

// ---------- K4: q_norm[b,h,l] = sum_d Q[b,l,h*64+d]^2 ----------
__global__ void qnorm_kernel(const float* __restrict__ PROJ, float* __restrict__ qn){
  int g = blockIdx.x * 256 + threadIdx.x;   // 65536
  int b = g >> 15, rem = g & 32767, h = rem >> 11, l = rem & 2047;
  const float* q = PROJ + (size_t)(b * 2048 + l) * 1024 + h * 64;
  float s = 0.f;
#pragma unroll 8
  for (int d = 0; d < 64; ++d){ float x = q[d]; s += x * x; }
  qn[(size_t)(b * 16 + h) * 2048 + l] = s;
}

// ---------- K5: iterative top-u argmax per (b,h); tie -> lower index ----------
__global__ void topk_kernel(const float* __restrict__ qn, int* __restrict__ topk,
                            unsigned char* __restrict__ seli, unsigned int* __restrict__ hmask,
                            const int* __restrict__ qvlp){
  int bh = blockIdx.x; int b = bh >> 4, h = bh & 15;
  int u = compute_u(qvlp[0]);
  __shared__ float v[2048];
  __shared__ float rv[256];
  __shared__ int ri[256];
  int t = threadIdx.x;
  for (int j = t; j < 2048; j += 256) v[j] = qn[(size_t)bh * 2048 + j];
  __syncthreads();
  for (int it = 0; it < u; ++it){
    float bvv = -3.4e38f; int bi = 2048;
    for (int j = t; j < 2048; j += 256){ float x = v[j]; if (x > bvv){ bvv = x; bi = j; } }
    rv[t] = bvv; ri[t] = bi;
    __syncthreads();
    for (int s = 128; s > 0; s >>= 1){
      if (t < s){
        if (rv[t+s] > rv[t] || (rv[t+s] == rv[t] && ri[t+s] < ri[t])){ rv[t] = rv[t+s]; ri[t] = ri[t+s]; }
      }
      __syncthreads();
    }
    if (t == 0){
      int idx = ri[0];
      topk[bh * 64 + it] = idx;
      seli[(size_t)bh * 2048 + idx] = (unsigned char)it;
      atomicOr(&hmask[b * 2048 + idx], 1u << h);
      v[idx] = -3.4e38f;
    }
    __syncthreads();
  }
}

// ---------- K6: scores for selected rows; bf16 round + bf16 mask add ----------
__global__ void scores_kernel(const float* __restrict__ PROJ, const int* __restrict__ topk,
                              const float* __restrict__ maskp, u16* __restrict__ sc,
                              const int* __restrict__ qvlp, const int* __restrict__ kvlp){
  int bh = blockIdx.y; int b = bh >> 4, h = bh & 15;
  int kvlv = kvlp[0]; if (kvlv > 2048) kvlv = 2048; if (kvlv < 0) kvlv = 0;
  int u = compute_u(qvlp[0]);
  int k0 = blockIdx.x * 128;
  if (k0 >= kvlv) return;
  int kcnt = kvlv - k0; if (kcnt > 128) kcnt = 128;
  int t = threadIdx.x;
  __shared__ int idx_l[64];
  __shared__ float qld[64 * 64];
  __shared__ float kld[128 * 65];
  const float* Q = PROJ;
  const float* K = PROJ + 4194304;
  if (t < u) idx_l[t] = topk[bh * 64 + t];
  __syncthreads();
  for (int e = t; e < u * 64; e += 256){
    int i = e >> 6, d = e & 63;
    qld[e] = Q[(size_t)(b * 2048 + idx_l[i]) * 1024 + h * 64 + d];
  }
  for (int e = t; e < 128 * 64; e += 256){
    int kk = e >> 6, d = e & 63;
    float vv = (kk < kcnt) ? K[(size_t)(b * 2048 + k0 + kk) * 1024 + h * 64 + d] : 0.f;
    kld[kk * 65 + d] = vv;
  }
  __syncthreads();
  for (int e = t; e < u * 128; e += 256){
    int i = e >> 7, kk = e & 127;
    if (kk >= kcnt) continue;
    const float* qr = &qld[i * 64];
    const float* kr = &kld[kk * 65];
    float s = 0.f;
#pragma unroll 8
    for (int d = 0; d < 64; ++d) s += qr[d] * kr[d];
    s *= 0.125f;                          // / sqrt(64)
    int l = idx_l[i]; int k = k0 + kk;
    u16 xb = f2bf(s);                     // scores.astype(bf16)
    u16 mb = f2bf(maskp[(size_t)l * 2048 + k]);   // attn_mask.astype(bf16) (kpm=0 here)
    u16 xm = f2bf(bf2f(xb) + bf2f(mb));   // bf16 add
    sc[(size_t)(bh * 64 + i) * 2048 + k] = xm;
  }
}

// ---------- K7: exact bf16 softmax emulation; p written in place ----------
__global__ void softmax_kernel(u16* __restrict__ sc, const int* __restrict__ qvlp,
                               const int* __restrict__ kvlp){
  int bh = blockIdx.y, i = blockIdx.x;
  int u = compute_u(qvlp[0]);
  if (i >= u) return;
  int kvlv = kvlp[0]; if (kvlv > 2048) kvlv = 2048; if (kvlv < 0) kvlv = 0;
  u16* row = sc + (size_t)(bh * 64 + i) * 2048;
  int t = threadIdx.x;
  float x[8];
  float lm = -3.4e38f;
#pragma unroll
  for (int j = 0; j < 8; ++j){
    int k = t + j * 256;
    x[j] = (k < kvlv) ? bf2f(row[k]) : -3.4e38f;
    lm = fmaxf(lm, x[j]);
  }
  __shared__ float red[256];
  red[t] = lm; __syncthreads();
  for (int s = 128; s > 0; s >>= 1){ if (t < s) red[t] = fmaxf(red[t], red[t+s]); __syncthreads(); }
  float m = red[0];
  __syncthreads();
  float e[8]; float ls = 0.f;
#pragma unroll
  for (int j = 0; j < 8; ++j){
    int k = t + j * 256;
    if (k < kvlv){
      u16 ub = f2bf(x[j] - m);            // bf16 subtract
      u16 eb = f2bf(expf(bf2f(ub)));      // bf16 exp
      e[j] = bf2f(eb);
      ls += e[j];
    } else e[j] = 0.f;
  }
  red[t] = ls; __syncthreads();
  for (int s = 128; s > 0; s >>= 1){ if (t < s) red[t] += red[t+s]; __syncthreads(); }
  float S = red[0];                       // f32 accumulation (jnp.sum upcast)
  float Sb = bf2f(f2bf(S));               // downcast back to bf16
#pragma unroll
  for (int j = 0; j < 8; ++j){
    int k = t + j * 256;
    if (k < 2048) row[k] = (k < kvlv) ? f2bf(e[j] / Sb) : (u16)0;   // bf16 divide
  }
}

// ---------- K8a: PV partials, LDS-tiled split-K ----------
// grid (kc<16, bh<32), block 256. Stages V[128][64] f32 + P[u][128] f32 in LDS.
// part[kc][bh][r][d] (aliased over X1 scratch, dead after gemm_proj).
#define PV_KC 128
__global__ __launch_bounds__(256, 2) void pv_kernel2(
    const float* __restrict__ PROJ, const u16* __restrict__ probs,
    float* __restrict__ part, const int* __restrict__ qvlp,
    const int* __restrict__ kvlp)
{
  int bh = blockIdx.y; int b = bh >> 4, h = bh & 15;
  int kvlv = kvlp[0]; if (kvlv > 2048) kvlv = 2048; if (kvlv < 0) kvlv = 0;
  int u = compute_u(qvlp[0]);
  int kc = blockIdx.x;
  int k0 = kc * PV_KC;
  if (k0 >= kvlv) return;
  int kcnt = kvlv - k0; if (kcnt > PV_KC) kcnt = PV_KC;
  const float* V = PROJ + 2 * 4194304;
  __shared__ __align__(16) float Vl[PV_KC * 64];   // 32 KB
  __shared__ __align__(16) float Pl[64 * PV_KC];   // 32 KB
  int t = threadIdx.x;
  // V tile (f32, coalesced float4); rows beyond kcnt -> 0
  for (int e = t; e < PV_KC * 16; e += 256){
    int kk = e >> 4, d4 = e & 15;
    f32x4 vv = {0.f, 0.f, 0.f, 0.f};
    if (kk < kcnt)
      vv = *reinterpret_cast<const f32x4*>(&V[(size_t)(b * 2048 + k0 + kk) * 1024 + h * 64 + d4 * 4]);
    *reinterpret_cast<f32x4*>(&Vl[kk * 64 + d4 * 4]) = vv;
  }
  // P tile: rows < u from probs (bf16->f32; zeros beyond kvlv already stored)
  for (int e = t; e < u * (PV_KC / 4); e += 256){
    int i = e / (PV_KC / 4), kq = e % (PV_KC / 4);
    ushort4 pv = *reinterpret_cast<const ushort4*>(
        probs + (size_t)(bh * 64 + i) * 2048 + k0 + kq * 4);
    float* dst = &Pl[i * PV_KC + kq * 4];
    dst[0] = bf2f(pv.x); dst[1] = bf2f(pv.y); dst[2] = bf2f(pv.z); dst[3] = bf2f(pv.w);
  }
  // zero P rows >= u (read unconditionally in compute loop)
  for (int e = u * PV_KC + t; e < 64 * PV_KC; e += 256) Pl[e] = 0.f;
  __syncthreads();

  int g4 = t >> 4, d4 = t & 15;      // row-group, d-slice
  f32x4 acc[4] = {{0,0,0,0},{0,0,0,0},{0,0,0,0},{0,0,0,0}};
  for (int k = 0; k < PV_KC; k += 4){
    f32x4 v0 = *reinterpret_cast<const f32x4*>(&Vl[(k + 0) * 64 + d4 * 4]);
    f32x4 v1 = *reinterpret_cast<const f32x4*>(&Vl[(k + 1) * 64 + d4 * 4]);
    f32x4 v2 = *reinterpret_cast<const f32x4*>(&Vl[(k + 2) * 64 + d4 * 4]);
    f32x4 v3 = *reinterpret_cast<const f32x4*>(&Vl[(k + 3) * 64 + d4 * 4]);
#pragma unroll
    for (int s = 0; s < 4; ++s){
      int r = g4 + s * 16;
      f32x4 p = *reinterpret_cast<const f32x4*>(&Pl[r * PV_KC + k]);
      acc[s] += p.x * v0;
      acc[s] += p.y * v1;
      acc[s] += p.z * v2;
      acc[s] += p.w * v3;
    }
  }
#pragma unroll
  for (int s = 0; s < 4; ++s){
    int r = g4 + s * 16;
    if (r < u)
      *reinterpret_cast<f32x4*>(
          &part[(size_t)((kc * 32 + bh) * 64 + r) * 64 + d4 * 4]) = acc[s];
  }
}

// ---------- K8b: deterministic reduction of PV partials ----------
__global__ void pv_reduce(const float* __restrict__ part, float* __restrict__ ctx,
                          const int* __restrict__ qvlp, const int* __restrict__ kvlp){
  int bh = blockIdx.y, r = blockIdx.x;
  int u = compute_u(qvlp[0]);
  if (r >= u) return;
  int kvlv = kvlp[0]; if (kvlv > 2048) kvlv = 2048; if (kvlv < 0) kvlv = 0;
  int kcmax = (kvlv + PV_KC - 1) / PV_KC;
  int d = threadIdx.x;   // 64
  float s = 0.f;
  for (int kc = 0; kc < kcmax; ++kc)
    s += part[(size_t)((kc * 32 + bh) * 64 + r) * 64 + d];
  ctx[(size_t)(bh * 64 + r) * 64 + d] = s;
}

// ---------- K9: sparse output projection; unselected rows = bo ----------
__global__ void outproj_kernel(const float* __restrict__ ctx, const float* __restrict__ WoT,
                               const float* __restrict__ bo, const unsigned int* __restrict__ hmask,
                               const unsigned char* __restrict__ seli, float* __restrict__ out){
  int row = blockIdx.x;                 // b*2048 + l
  int b = row >> 11, l = row & 2047;
  int t = threadIdx.x;
  float acc[4];
#pragma unroll
  for (int r = 0; r < 4; ++r) acc[r] = bo[t + r * 256];
  unsigned int m = hmask[row];
  __shared__ float clds[64];
  while (m){
    int h = __ffs(m) - 1; m &= (m - 1);
    int i = (int)seli[(size_t)(b * 16 + h) * 2048 + l];
    __syncthreads();
    if (t < 64) clds[t] = ctx[(size_t)((b * 16 + h) * 64 + i) * 64 + t];
    __syncthreads();
    for (int j = 0; j < 64; ++j){
      float c = clds[j];
      const float* wrow = &WoT[(size_t)(h * 64 + j) * 1024];
#pragma unroll
      for (int r = 0; r < 4; ++r) acc[r] += c * wrow[t + r * 256];
    }
  }
  float* orow = out + (size_t)row * 1024;
#pragma unroll
  for (int r = 0; r < 4; ++r) orow[t + r * 256] = acc[r];
}

__global__ void fail_fill(float* o, int n){
  int i = blockIdx.x * 256 + threadIdx.x;
  if (i < n) o[i] = 12345.0f;
}

// ---------------------------------------------------------------------------
extern "C" void kernel_launch(void* const* d_in, const int* in_sizes, int n_in,
                              void* d_out, int out_size, void* d_ws, size_t ws_size,
                              hipStream_t stream)
{
  const float* query = (const float*)d_in[0];
  const float* key   = (const float*)d_in[1];
  const float* value = (const float*)d_in[2];
  const float* maskp = (const float*)d_in[3];
  const float* Wq = (const float*)d_in[4];
  const float* bq = (const float*)d_in[5];
  const float* Wk = (const float*)d_in[6];
  const float* bk = (const float*)d_in[7];
  const float* Wv = (const float*)d_in[8];
  const float* bv = (const float*)d_in[9];
  const float* Wo = (const float*)d_in[10];
  const float* bo = (const float*)d_in[11];
  const int* qvl = (const int*)d_in[12];
  const int* kvl = (const int*)d_in[13];
  float* out = (float*)d_out;

  char* ws = (char*)d_ws;
  size_t off = 0;
  auto alloc = [&](size_t bytes) -> void* {
    void* p = ws + off;
    off = (off + bytes + 255) & ~(size_t)255;
    return p;
  };
  u16* X1 = (u16*)alloc(3ull * 4194304 * 2);
  u16* X2 = (u16*)alloc(3ull * 4194304 * 2);
  u16* X3 = (u16*)alloc(1ull * 4194304 * 2);
  u16* W1 = (u16*)alloc(3ull * 1048576 * 2);
  u16* W2 = (u16*)alloc(3ull * 1048576 * 2);
  u16* W3 = (u16*)alloc(1ull * 1048576 * 2);
  float* PROJ = (float*)alloc(3ull * 4194304 * 4);
  float* WOT  = (float*)alloc(4194304ull);
  float* QN   = (float*)alloc(2ull * 16 * 2048 * 4);
  int*   TOPK = (int*)alloc(2ull * 16 * 64 * 4);
  unsigned char* SELI = (unsigned char*)alloc(2ull * 16 * 2048);
  unsigned int* HMASK = (unsigned int*)alloc(2ull * 2048 * 4);
  u16*   SC   = (u16*)alloc(2048ull * 2048 * 2);
  float* CTX  = (float*)alloc(2048ull * 64 * 4);

  // PV partials alias X1 (24 MB region, dead after gemm_proj): 16*32*64*64*4 = 8.4 MB
  float* PART = (float*)X1;

  if (ws_size < off){
    fail_fill<<<(out_size + 255) / 256, 256, 0, stream>>>(out, out_size);
    return;
  }

  hipMemsetAsync(SELI, 0xFF, 2ull * 16 * 2048, stream);
  hipMemsetAsync(HMASK, 0, 2ull * 2048 * 4, stream);

  expand_kernel<<<15360, 256, 0, stream>>>(query, key, value, Wq, Wk, Wv,
                                           X1, X2, X3, W1, W2, W3);
  wot_kernel<<<dim3(32, 32), dim3(32, 8), 0, stream>>>(Wo, WOT);
  gemm_proj<<<dim3(8, 32, 3), 256, 0, stream>>>(X1, X2, X3, W1, W2, W3, bq, bk, bv, PROJ);
  qnorm_kernel<<<256, 256, 0, stream>>>(PROJ, QN);
  topk_kernel<<<32, 256, 0, stream>>>(QN, TOPK, SELI, HMASK, qvl);
  scores_kernel<<<dim3(16, 32), 256, 0, stream>>>(PROJ, TOPK, maskp, SC, qvl, kvl);
  softmax_kernel<<<dim3(64, 32), 256, 0, stream>>>(SC, qvl, kvl);
  pv_kernel2<<<dim3(16, 32), 256, 0, stream>>>(PROJ, SC, PART, qvl, kvl);
  pv_reduce<<<dim3(64, 32), 64, 0, stream>>>(PART, CTX, qvl, kvl);
  outproj_kernel<<<4096, 256, 0, stream>>>(CTX, WOT, bo, HMASK, SELI, out);
}

// Round 3
// 337.106 us; speedup vs baseline: 2.1094x; 1.8205x over previous
//
#include <hip/hip_runtime.h>

typedef unsigned short u16;
typedef __bf16 bf16x8 __attribute__((ext_vector_type(8)));
typedef float f32x4 __attribute__((ext_vector_type(4)));

// ---------- numeric helpers (RNE f32<->bf16, matching XLA/ml_dtypes) ----------
__device__ __forceinline__ u16 f2bf(float f){
  unsigned int x = __float_as_uint(f);
  unsigned int r = (x + 0x7FFFu + ((x >> 16) & 1u)) >> 16;
  return (u16)r;
}
__device__ __forceinline__ float bf2f(u16 u){
  return __uint_as_float(((unsigned int)u) << 16);
}
__device__ __forceinline__ int compute_u(int qvlv){
  int mm = qvlv > 2 ? qvlv : 2;
  int u = (int)(5.0 * log((double)mm));   // FACTOR=5.0, python int() truncation
  if (u < 1) u = 1;
  if (u > 64) u = 64;
  return u;
}
__device__ __forceinline__ void gload_lds16(const void* g, void* l){
  __builtin_amdgcn_global_load_lds(
      (const __attribute__((address_space(1))) void*)g,
      (__attribute__((address_space(3))) void*)l, 16, 0, 0);
}

// ---------- K1: split f32 -> 3 bf16 levels (X for q/k/v, W for Wq/Wk/Wv) ----------
__global__ void expand_kernel(const float* __restrict__ xq, const float* __restrict__ xk,
                              const float* __restrict__ xv,
                              const float* __restrict__ wq, const float* __restrict__ wk,
                              const float* __restrict__ wv,
                              u16* __restrict__ X1, u16* __restrict__ X2, u16* __restrict__ X3,
                              u16* __restrict__ W1, u16* __restrict__ W2, u16* __restrict__ W3)
{
  size_t g = (size_t)blockIdx.x * 256 + threadIdx.x;  // one group = 4 floats
  const float* src; u16 *d1, *d2, *d3;
  if (g < 3145728ull) {                 // X part: 3 * 4194304 / 4
    int p = (int)(g >> 20);
    size_t e = (g & 1048575ull) * 4;
    src = (p == 0 ? xq : (p == 1 ? xk : xv)) + e;
    size_t o = (size_t)p * 4194304ull + e;
    d1 = X1 + o; d2 = X2 + o; d3 = (p == 0) ? (X3 + e) : (u16*)0;
  } else {                              // W part: 3 * 1048576 / 4
    size_t wg = g - 3145728ull;
    int p = (int)(wg >> 18);
    size_t e = (wg & 262143ull) * 4;
    src = (p == 0 ? wq : (p == 1 ? wk : wv)) + e;
    size_t o = (size_t)p * 1048576ull + e;
    d1 = W1 + o; d2 = W2 + o; d3 = (p == 0) ? (W3 + e) : (u16*)0;
  }
  float4 x = *reinterpret_cast<const float4*>(src);
  float xs[4] = {x.x, x.y, x.z, x.w};
  u16 h1[4], h2[4], h3[4];
#pragma unroll
  for (int i = 0; i < 4; ++i){
    float v = xs[i];
    u16 a = f2bf(v);  float r1 = v  - bf2f(a);
    u16 b = f2bf(r1); float r2 = r1 - bf2f(b);
    u16 c = f2bf(r2);
    h1[i] = a; h2[i] = b; h3[i] = c;
  }
  *reinterpret_cast<ushort4*>(d1) = make_ushort4(h1[0], h1[1], h1[2], h1[3]);
  *reinterpret_cast<ushort4*>(d2) = make_ushort4(h2[0], h2[1], h2[2], h2[3]);
  if (d3) *reinterpret_cast<ushort4*>(d3) = make_ushort4(h3[0], h3[1], h3[2], h3[3]);
}

// ---------- K2: WoT[j][d] = Wo[d][j] ----------
__global__ void wot_kernel(const float* __restrict__ Wo, float* __restrict__ WoT){
  __shared__ float tile[32][33];
  int tx = threadIdx.x, ty = threadIdx.y;   // 32 x 8
  int bx = blockIdx.x * 32, by = blockIdx.y * 32;
#pragma unroll
  for (int r = 0; r < 4; ++r)
    tile[ty + r*8][tx] = Wo[(size_t)(by + ty + r*8) * 1024 + bx + tx];
  __syncthreads();
#pragma unroll
  for (int r = 0; r < 4; ++r)
    WoT[(size_t)(bx + ty + r*8) * 1024 + by + tx] = tile[tx][ty + r*8];
}

// ---------- K3: split-precision bf16 MFMA GEMM  C = X @ W^T + bias ----------
// z=0: Q (6 terms), z=1: K (3 terms) -> f32 PROJ
// z=2: V (3 terms) -> VT split-bf16 transposed: VT[b,h][dd=128][k=2048]
//      dd in [0,64) = hi plane, [64,128) = lo plane (aliases PROJ z-2 slice)
__global__ __launch_bounds__(256, 3) void gemm_proj(
    const u16* __restrict__ X1, const u16* __restrict__ X2, const u16* __restrict__ X3,
    const u16* __restrict__ W1, const u16* __restrict__ W2, const u16* __restrict__ W3,
    const float* __restrict__ bq, const float* __restrict__ bk, const float* __restrict__ bv,
    float* __restrict__ PROJ)
{
  int z = blockIdx.z;
  const u16* Xl0 = X1 + (size_t)z * 4194304;
  const u16* Xl1 = X2 + (size_t)z * 4194304;
  const u16* Xl2 = X3;                       // only valid/used when z==0
  const u16* Wl0 = W1 + (size_t)z * 1048576;
  const u16* Wl1 = W2 + (size_t)z * 1048576;
  const u16* Wl2 = W3;
  const float* bias = (z == 0) ? bq : (z == 1 ? bk : bv);
  float* C = PROJ + (size_t)z * 4194304;
  int nt = (z == 0) ? 6 : 3;
  const int aPack = 2128;  // levels {0,0,1,1,0,2} packed 2b
  const int bPack = 580;   // levels {0,1,0,1,2,0}

  __shared__ __align__(16) u16 As[128 * 32];
  __shared__ __align__(16) u16 Bs[128 * 32];
  int t = threadIdx.x;
  int wave = t >> 6, lane = t & 63;
  int wm = wave >> 1, wn = wave & 1;
  f32x4 acc[4][4] = {};
  int KT = nt * 32;
  for (int kt = 0; kt < KT; ++kt){
    int term = kt >> 5;
    int pk = (kt & 31) * 32;
    int alv = (aPack >> (2 * term)) & 3;
    int blv = (bPack >> (2 * term)) & 3;
    const u16* Ab = (alv == 0) ? Xl0 : (alv == 1 ? Xl1 : Xl2);
    const u16* Bb = (blv == 0) ? Wl0 : (blv == 1 ? Wl1 : Wl2);
#pragma unroll
    for (int i = 0; i < 2; ++i){
      int c = i * 256 + t;
      const u16* src = Ab + (size_t)(blockIdx.y * 128 + (c >> 2)) * 1024 + pk + (c & 3) * 8;
      gload_lds16(src, &As[(i * 256 + wave * 64) * 8]);
    }
#pragma unroll
    for (int i = 0; i < 2; ++i){
      int c = i * 256 + t;
      const u16* src = Bb + (size_t)(blockIdx.x * 128 + (c >> 2)) * 1024 + pk + (c & 3) * 8;
      gload_lds16(src, &Bs[(i * 256 + wave * 64) * 8]);
    }
    __syncthreads();
    bf16x8 af[4], bg[4];
#pragma unroll
    for (int m = 0; m < 4; ++m){
      int r = wm * 64 + m * 16 + (lane & 15);
      af[m] = *reinterpret_cast<const bf16x8*>(&As[r * 32 + (lane >> 4) * 8]);
    }
#pragma unroll
    for (int n = 0; n < 4; ++n){
      int r = wn * 64 + n * 16 + (lane & 15);
      bg[n] = *reinterpret_cast<const bf16x8*>(&Bs[r * 32 + (lane >> 4) * 8]);
    }
#pragma unroll
    for (int m = 0; m < 4; ++m)
#pragma unroll
      for (int n = 0; n < 4; ++n)
        acc[m][n] = __builtin_amdgcn_mfma_f32_16x16x32_bf16(af[m], bg[n], acc[m][n], 0, 0, 0);
    __syncthreads();
  }
  if (z < 2){
#pragma unroll
    for (int m = 0; m < 4; ++m){
      int row0 = blockIdx.y * 128 + wm * 64 + m * 16 + (lane >> 4) * 4;
#pragma unroll
      for (int n = 0; n < 4; ++n){
        int col = blockIdx.x * 128 + wn * 64 + n * 16 + (lane & 15);
        float bb = bias[col];
#pragma unroll
        for (int j = 0; j < 4; ++j)
          C[(size_t)(row0 + j) * 1024 + col] = acc[m][n][j] + bb;
      }
    }
  } else {
    u16* VT = (u16*)C;   // 16.78 MB region, exactly fits [32][128][2048] u16
#pragma unroll
    for (int m = 0; m < 4; ++m){
      int r0 = blockIdx.y * 128 + wm * 64 + m * 16 + (lane >> 4) * 4;
      int b = r0 >> 11, kb = r0 & 2047;
#pragma unroll
      for (int n = 0; n < 4; ++n){
        int c = blockIdx.x * 128 + wn * 64 + n * 16 + (lane & 15);
        float bb = bias[c];
        int h = c >> 6, d = c & 63;
        u16 hi[4], lo[4];
#pragma unroll
        for (int j = 0; j < 4; ++j){
          float v = acc[m][n][j] + bb;
          hi[j] = f2bf(v);
          lo[j] = f2bf(v - bf2f(hi[j]));
        }
        size_t base = ((size_t)(b * 16 + h) * 128) * 2048 + (size_t)kb;
        *reinterpret_cast<ushort4*>(&VT[base + (size_t)d * 2048]) =
            make_ushort4(hi[0], hi[1], hi[2], hi[3]);
        *reinterpret_cast<ushort4*>(&VT[base + (size_t)(64 + d) * 2048]) =
            make_ushort4(lo[0], lo[1], lo[2], lo[3]);
      }
    }
  }
}

// ---------- K4: q_norm[b,h,l] = sum_d Q[b,l,h*64+d]^2 ----------
__global__ void qnorm_kernel(const float* __restrict__ PROJ, float* __restrict__ qn){
  int g = blockIdx.x * 256 + threadIdx.x;   // 65536
  int b = g >> 15, rem = g & 32767, h = rem >> 11, l = rem & 2047;
  const float* q = PROJ + (size_t)(b * 2048 + l) * 1024 + h * 64;
  float s = 0.f;
#pragma unroll 8
  for (int d = 0; d < 64; ++d){ float x = q[d]; s += x * x; }
  qn[(size_t)(b * 16 + h) * 2048 + l] = s;
}

// ---------- K5: iterative top-u argmax per (b,h); tie -> lower index ----------
__global__ void topk_kernel(const float* __restrict__ qn, int* __restrict__ topk,
                            unsigned char* __restrict__ seli, unsigned int* __restrict__ hmask,
                            const int* __restrict__ qvlp){
  int bh = blockIdx.x; int b = bh >> 4, h = bh & 15;
  int u = compute_u(qvlp[0]);
  __shared__ float v[2048];
  __shared__ float rv[256];
  __shared__ int ri[256];
  int t = threadIdx.x;
  for (int j = t; j < 2048; j += 256) v[j] = qn[(size_t)bh * 2048 + j];
  __syncthreads();
  for (int it = 0; it < u; ++it){
    float bvv = -3.4e38f; int bi = 2048;
    for (int j = t; j < 2048; j += 256){ float x = v[j]; if (x > bvv){ bvv = x; bi = j; } }
    rv[t] = bvv; ri[t] = bi;
    __syncthreads();
    for (int s = 128; s > 0; s >>= 1){
      if (t < s){
        if (rv[t+s] > rv[t] || (rv[t+s] == rv[t] && ri[t+s] < ri[t])){ rv[t] = rv[t+s]; ri[t] = ri[t+s]; }
      }
      __syncthreads();
    }
    if (t == 0){
      int idx = ri[0];
      topk[bh * 64 + it] = idx;
      seli[(size_t)bh * 2048 + idx] = (unsigned char)it;
      atomicOr(&hmask[b * 2048 + idx], 1u << h);
      v[idx] = -3.4e38f;
    }
    __syncthreads();
  }
}

// ---------- K6: scores for selected rows; bf16 round + bf16 mask add ----------
__global__ void scores_kernel(const float* __restrict__ PROJ, const int* __restrict__ topk,
                              const float* __restrict__ maskp, u16* __restrict__ sc,
                              const int* __restrict__ qvlp, const int* __restrict__ kvlp){
  int bh = blockIdx.y; int b = bh >> 4, h = bh & 15;
  int kvlv = kvlp[0]; if (kvlv > 2048) kvlv = 2048; if (kvlv < 0) kvlv = 0;
  int u = compute_u(qvlp[0]);
  int k0 = blockIdx.x * 128;
  if (k0 >= kvlv) return;
  int kcnt = kvlv - k0; if (kcnt > 128) kcnt = 128;
  int t = threadIdx.x;
  __shared__ int idx_l[64];
  __shared__ float qld[64 * 64];
  __shared__ float kld[128 * 65];
  const float* Q = PROJ;
  const float* K = PROJ + 4194304;
  if (t < u) idx_l[t] = topk[bh * 64 + t];
  __syncthreads();
  for (int e = t; e < u * 64; e += 256){
    int i = e >> 6, d = e & 63;
    qld[e] = Q[(size_t)(b * 2048 + idx_l[i]) * 1024 + h * 64 + d];
  }
  for (int e = t; e < 128 * 64; e += 256){
    int kk = e >> 6, d = e & 63;
    float vv = (kk < kcnt) ? K[(size_t)(b * 2048 + k0 + kk) * 1024 + h * 64 + d] : 0.f;
    kld[kk * 65 + d] = vv;
  }
  __syncthreads();
  for (int e = t; e < u * 128; e += 256){
    int i = e >> 7, kk = e & 127;
    if (kk >= kcnt) continue;
    const float* qr = &qld[i * 64];
    const float* kr = &kld[kk * 65];
    float s = 0.f;
#pragma unroll 8
    for (int d = 0; d < 64; ++d) s += qr[d] * kr[d];
    s *= 0.125f;                          // / sqrt(64)
    int l = idx_l[i]; int k = k0 + kk;
    u16 xb = f2bf(s);                     // scores.astype(bf16)
    u16 mb = f2bf(maskp[(size_t)l * 2048 + k]);   // attn_mask.astype(bf16) (kpm=0 here)
    u16 xm = f2bf(bf2f(xb) + bf2f(mb));   // bf16 add
    sc[(size_t)(bh * 64 + i) * 2048 + k] = xm;
  }
}

// ---------- K7: exact bf16 softmax emulation; p written in place ----------
__global__ void softmax_kernel(u16* __restrict__ sc, const int* __restrict__ qvlp,
                               const int* __restrict__ kvlp){
  int bh = blockIdx.y, i = blockIdx.x;
  int u = compute_u(qvlp[0]);
  if (i >= u) return;
  int kvlv = kvlp[0]; if (kvlv > 2048) kvlv = 2048; if (kvlv < 0) kvlv = 0;
  u16* row = sc + (size_t)(bh * 64 + i) * 2048;
  int t = threadIdx.x;
  float x[8];
  float lm = -3.4e38f;
#pragma unroll
  for (int j = 0; j < 8; ++j){
    int k = t + j * 256;
    x[j] = (k < kvlv) ? bf2f(row[k]) : -3.4e38f;
    lm = fmaxf(lm, x[j]);
  }
  __shared__ float red[256];
  red[t] = lm; __syncthreads();
  for (int s = 128; s > 0; s >>= 1){ if (t < s) red[t] = fmaxf(red[t], red[t+s]); __syncthreads(); }
  float m = red[0];
  __syncthreads();
  float e[8]; float ls = 0.f;
#pragma unroll
  for (int j = 0; j < 8; ++j){
    int k = t + j * 256;
    if (k < kvlv){
      u16 ub = f2bf(x[j] - m);            // bf16 subtract
      u16 eb = f2bf(expf(bf2f(ub)));      // bf16 exp
      e[j] = bf2f(eb);
      ls += e[j];
    } else e[j] = 0.f;
  }
  red[t] = ls; __syncthreads();
  for (int s = 128; s > 0; s >>= 1){ if (t < s) red[t] += red[t+s]; __syncthreads(); }
  float S = red[0];                       // f32 accumulation (jnp.sum upcast)
  float Sb = bf2f(f2bf(S));               // downcast back to bf16
#pragma unroll
  for (int j = 0; j < 8; ++j){
    int k = t + j * 256;
    if (k < 2048) row[k] = (k < kvlv) ? f2bf(e[j] / Sb) : (u16)0;   // bf16 divide
  }
}

// ---------- K8a: PV via MFMA, no LDS. part[kc][bh][64 rows][64 d] ----------
// A = P rows (exact bf16 already), B = VT hi/lo planes. P rows >= u are
// finite garbage -> results discarded (only r<u consumed downstream).
__global__ void pv_mfma(const u16* __restrict__ probs, const u16* __restrict__ VT,
                        float* __restrict__ part, const int* __restrict__ kvlp)
{
  int bh = blockIdx.y; int b = bh >> 4, h = bh & 15;
  int kvlv = kvlp[0]; if (kvlv > 2048) kvlv = 2048; if (kvlv < 0) kvlv = 0;
  int kc = blockIdx.x;
  int k0 = kc * 128;
  if (k0 >= kvlv) return;
  int t = threadIdx.x, w = t >> 6, lane = t & 63;
  int lr = lane & 15, lk = lane >> 4;
  const u16* Pb = probs + (size_t)bh * 64 * 2048;
  const u16* Vb = VT + (size_t)(b * 16 + h) * 128 * 2048;
  f32x4 acc[4] = {};
#pragma unroll
  for (int ks = 0; ks < 4; ++ks){
    int kk = k0 + ks * 32 + lk * 8;
    bf16x8 A0 = *reinterpret_cast<const bf16x8*>(Pb + (size_t)(lr     ) * 2048 + kk);
    bf16x8 A1 = *reinterpret_cast<const bf16x8*>(Pb + (size_t)(lr + 16) * 2048 + kk);
    bf16x8 A2 = *reinterpret_cast<const bf16x8*>(Pb + (size_t)(lr + 32) * 2048 + kk);
    bf16x8 A3 = *reinterpret_cast<const bf16x8*>(Pb + (size_t)(lr + 48) * 2048 + kk);
    bf16x8 Bh = *reinterpret_cast<const bf16x8*>(Vb + (size_t)(w * 16 + lr     ) * 2048 + kk);
    bf16x8 Bl = *reinterpret_cast<const bf16x8*>(Vb + (size_t)(w * 16 + lr + 64) * 2048 + kk);
    acc[0] = __builtin_amdgcn_mfma_f32_16x16x32_bf16(A0, Bh, acc[0], 0, 0, 0);
    acc[1] = __builtin_amdgcn_mfma_f32_16x16x32_bf16(A1, Bh, acc[1], 0, 0, 0);
    acc[2] = __builtin_amdgcn_mfma_f32_16x16x32_bf16(A2, Bh, acc[2], 0, 0, 0);
    acc[3] = __builtin_amdgcn_mfma_f32_16x16x32_bf16(A3, Bh, acc[3], 0, 0, 0);
    acc[0] = __builtin_amdgcn_mfma_f32_16x16x32_bf16(A0, Bl, acc[0], 0, 0, 0);
    acc[1] = __builtin_amdgcn_mfma_f32_16x16x32_bf16(A1, Bl, acc[1], 0, 0, 0);
    acc[2] = __builtin_amdgcn_mfma_f32_16x16x32_bf16(A2, Bl, acc[2], 0, 0, 0);
    acc[3] = __builtin_amdgcn_mfma_f32_16x16x32_bf16(A3, Bl, acc[3], 0, 0, 0);
  }
  float* pc = part + (size_t)(kc * 32 + bh) * 64 * 64;
#pragma unroll
  for (int m = 0; m < 4; ++m){
    int row = m * 16 + lk * 4;
#pragma unroll
    for (int j = 0; j < 4; ++j)
      pc[(size_t)(row + j) * 64 + w * 16 + lr] = acc[m][j];
  }
}

// ---------- K8b: deterministic reduction of PV partials ----------
__global__ void pv_reduce(const float* __restrict__ part, float* __restrict__ ctx,
                          const int* __restrict__ qvlp, const int* __restrict__ kvlp){
  int bh = blockIdx.y, r = blockIdx.x;
  int u = compute_u(qvlp[0]);
  if (r >= u) return;
  int kvlv = kvlp[0]; if (kvlv > 2048) kvlv = 2048; if (kvlv < 0) kvlv = 0;
  int kcmax = (kvlv + 127) / 128;
  int d = threadIdx.x;   // 64
  float s = 0.f;
  for (int kc = 0; kc < kcmax; ++kc)
    s += part[(size_t)((kc * 32 + bh) * 64 + r) * 64 + d];
  ctx[(size_t)(bh * 64 + r) * 64 + d] = s;
}

// ---------- K9: sparse output projection; unselected rows = bo ----------
__global__ void outproj_kernel(const float* __restrict__ ctx, const float* __restrict__ WoT,
                               const float* __restrict__ bo, const unsigned int* __restrict__ hmask,
                               const unsigned char* __restrict__ seli, float* __restrict__ out){
  int row = blockIdx.x;                 // b*2048 + l
  int b = row >> 11, l = row & 2047;
  int t = threadIdx.x;
  float acc[4];
#pragma unroll
  for (int r = 0; r < 4; ++r) acc[r] = bo[t + r * 256];
  unsigned int m = hmask[row];
  __shared__ float clds[64];
  while (m){
    int h = __ffs(m) - 1; m &= (m - 1);
    int i = (int)seli[(size_t)(b * 16 + h) * 2048 + l];
    __syncthreads();
    if (t < 64) clds[t] = ctx[(size_t)((b * 16 + h) * 64 + i) * 64 + t];
    __syncthreads();
    for (int j = 0; j < 64; ++j){
      float c = clds[j];
      const float* wrow = &WoT[(size_t)(h * 64 + j) * 1024];
#pragma unroll
      for (int r = 0; r < 4; ++r) acc[r] += c * wrow[t + r * 256];
    }
  }
  float* orow = out + (size_t)row * 1024;
#pragma unroll
  for (int r = 0; r < 4; ++r) orow[t + r * 256] = acc[r];
}

__global__ void fail_fill(float* o, int n){
  int i = blockIdx.x * 256 + threadIdx.x;
  if (i < n) o[i] = 12345.0f;
}

// ---------------------------------------------------------------------------
extern "C" void kernel_launch(void* const* d_in, const int* in_sizes, int n_in,
                              void* d_out, int out_size, void* d_ws, size_t ws_size,
                              hipStream_t stream)
{
  const float* query = (const float*)d_in[0];
  const float* key   = (const float*)d_in[1];
  const float* value = (const float*)d_in[2];
  const float* maskp = (const float*)d_in[3];
  const float* Wq = (const float*)d_in[4];
  const float* bq = (const float*)d_in[5];
  const float* Wk = (const float*)d_in[6];
  const float* bk = (const float*)d_in[7];
  const float* Wv = (const float*)d_in[8];
  const float* bv = (const float*)d_in[9];
  const float* Wo = (const float*)d_in[10];
  const float* bo = (const float*)d_in[11];
  const int* qvl = (const int*)d_in[12];
  const int* kvl = (const int*)d_in[13];
  float* out = (float*)d_out;

  char* ws = (char*)d_ws;
  size_t off = 0;
  auto alloc = [&](size_t bytes) -> void* {
    void* p = ws + off;
    off = (off + bytes + 255) & ~(size_t)255;
    return p;
  };
  u16* X1 = (u16*)alloc(3ull * 4194304 * 2);
  u16* X2 = (u16*)alloc(3ull * 4194304 * 2);
  u16* X3 = (u16*)alloc(1ull * 4194304 * 2);
  u16* W1 = (u16*)alloc(3ull * 1048576 * 2);
  u16* W2 = (u16*)alloc(3ull * 1048576 * 2);
  u16* W3 = (u16*)alloc(1ull * 1048576 * 2);
  float* PROJ = (float*)alloc(3ull * 4194304 * 4);
  float* WOT  = (float*)alloc(4194304ull);
  float* QN   = (float*)alloc(2ull * 16 * 2048 * 4);
  int*   TOPK = (int*)alloc(2ull * 16 * 64 * 4);
  unsigned char* SELI = (unsigned char*)alloc(2ull * 16 * 2048);
  unsigned int* HMASK = (unsigned int*)alloc(2ull * 2048 * 4);
  u16*   SC   = (u16*)alloc(2048ull * 2048 * 2);
  float* CTX  = (float*)alloc(2048ull * 64 * 4);

  // VT (split-bf16 transposed V) aliases the PROJ z==2 slice (exactly 16.78 MB)
  u16* VT = (u16*)(PROJ + 2ull * 4194304);
  // PV partials alias X1 (24 MB, dead after gemm_proj): 16*32*64*64*4 = 8.4 MB
  float* PART = (float*)X1;

  if (ws_size < off){
    fail_fill<<<(out_size + 255) / 256, 256, 0, stream>>>(out, out_size);
    return;
  }

  hipMemsetAsync(SELI, 0xFF, 2ull * 16 * 2048, stream);
  hipMemsetAsync(HMASK, 0, 2ull * 2048 * 4, stream);

  expand_kernel<<<15360, 256, 0, stream>>>(query, key, value, Wq, Wk, Wv,
                                           X1, X2, X3, W1, W2, W3);
  wot_kernel<<<dim3(32, 32), dim3(32, 8), 0, stream>>>(Wo, WOT);
  gemm_proj<<<dim3(8, 32, 3), 256, 0, stream>>>(X1, X2, X3, W1, W2, W3, bq, bk, bv, PROJ);
  qnorm_kernel<<<256, 256, 0, stream>>>(PROJ, QN);
  topk_kernel<<<32, 256, 0, stream>>>(QN, TOPK, SELI, HMASK, qvl);
  scores_kernel<<<dim3(16, 32), 256, 0, stream>>>(PROJ, TOPK, maskp, SC, qvl, kvl);
  softmax_kernel<<<dim3(64, 32), 256, 0, stream>>>(SC, qvl, kvl);
  pv_mfma<<<dim3(16, 32), 256, 0, stream>>>(SC, VT, PART, kvl);
  pv_reduce<<<dim3(64, 32), 64, 0, stream>>>(PART, CTX, qvl, kvl);
  outproj_kernel<<<4096, 256, 0, stream>>>(CTX, WOT, bo, HMASK, SELI, out);
}

// Round 4
// 324.289 us; speedup vs baseline: 2.1928x; 1.0395x over previous
//
#include <hip/hip_runtime.h>

typedef unsigned short u16;
typedef __bf16 bf16x8 __attribute__((ext_vector_type(8)));
typedef float f32x4 __attribute__((ext_vector_type(4)));

// ---------- numeric helpers (RNE f32<->bf16, matching XLA/ml_dtypes) ----------
__device__ __forceinline__ u16 f2bf(float f){
  unsigned int x = __float_as_uint(f);
  unsigned int r = (x + 0x7FFFu + ((x >> 16) & 1u)) >> 16;
  return (u16)r;
}
__device__ __forceinline__ float bf2f(u16 u){
  return __uint_as_float(((unsigned int)u) << 16);
}
__device__ __forceinline__ int compute_u(int qvlv){
  int mm = qvlv > 2 ? qvlv : 2;
  int u = (int)(5.0 * log((double)mm));   // FACTOR=5.0, python int() truncation
  if (u < 1) u = 1;
  if (u > 64) u = 64;
  return u;
}
__device__ __forceinline__ void gload_lds16(const void* g, void* l){
  __builtin_amdgcn_global_load_lds(
      (const __attribute__((address_space(1))) void*)g,
      (__attribute__((address_space(3))) void*)l, 16, 0, 0);
}

// ---------- K1: split f32 -> 3 bf16 levels (X for q/k/v, W for Wq/Wk/Wv) ----------
__global__ void expand_kernel(const float* __restrict__ xq, const float* __restrict__ xk,
                              const float* __restrict__ xv,
                              const float* __restrict__ wq, const float* __restrict__ wk,
                              const float* __restrict__ wv,
                              u16* __restrict__ X1, u16* __restrict__ X2, u16* __restrict__ X3,
                              u16* __restrict__ W1, u16* __restrict__ W2, u16* __restrict__ W3)
{
  size_t g = (size_t)blockIdx.x * 256 + threadIdx.x;  // one group = 4 floats
  const float* src; u16 *d1, *d2, *d3;
  if (g < 3145728ull) {                 // X part: 3 * 4194304 / 4
    int p = (int)(g >> 20);
    size_t e = (g & 1048575ull) * 4;
    src = (p == 0 ? xq : (p == 1 ? xk : xv)) + e;
    size_t o = (size_t)p * 4194304ull + e;
    d1 = X1 + o; d2 = X2 + o; d3 = (p == 0) ? (X3 + e) : (u16*)0;
  } else {                              // W part: 3 * 1048576 / 4
    size_t wg = g - 3145728ull;
    int p = (int)(wg >> 18);
    size_t e = (wg & 262143ull) * 4;
    src = (p == 0 ? wq : (p == 1 ? wk : wv)) + e;
    size_t o = (size_t)p * 1048576ull + e;
    d1 = W1 + o; d2 = W2 + o; d3 = (p == 0) ? (W3 + e) : (u16*)0;
  }
  float4 x = *reinterpret_cast<const float4*>(src);
  float xs[4] = {x.x, x.y, x.z, x.w};
  u16 h1[4], h2[4], h3[4];
#pragma unroll
  for (int i = 0; i < 4; ++i){
    float v = xs[i];
    u16 a = f2bf(v);  float r1 = v  - bf2f(a);
    u16 b = f2bf(r1); float r2 = r1 - bf2f(b);
    u16 c = f2bf(r2);
    h1[i] = a; h2[i] = b; h3[i] = c;
  }
  *reinterpret_cast<ushort4*>(d1) = make_ushort4(h1[0], h1[1], h1[2], h1[3]);
  *reinterpret_cast<ushort4*>(d2) = make_ushort4(h2[0], h2[1], h2[2], h2[3]);
  if (d3) *reinterpret_cast<ushort4*>(d3) = make_ushort4(h3[0], h3[1], h3[2], h3[3]);
}

// ---------- K2: WoT[j][d] = Wo[d][j] ----------
__global__ void wot_kernel(const float* __restrict__ Wo, float* __restrict__ WoT){
  __shared__ float tile[32][33];
  int tx = threadIdx.x, ty = threadIdx.y;   // 32 x 8
  int bx = blockIdx.x * 32, by = blockIdx.y * 32;
#pragma unroll
  for (int r = 0; r < 4; ++r)
    tile[ty + r*8][tx] = Wo[(size_t)(by + ty + r*8) * 1024 + bx + tx];
  __syncthreads();
#pragma unroll
  for (int r = 0; r < 4; ++r)
    WoT[(size_t)(bx + ty + r*8) * 1024 + by + tx] = tile[tx][ty + r*8];
}

// ---------- K3: split-precision bf16 MFMA GEMM  C = X @ W^T + bias ----------
// Term-shared staging: per K-chunk stage level-tiles once (A0,A1[,A2],B0,B1[,B2])
// then 48 (K/V) or 96 (Q) MFMAs per barrier-pair.
// LDS chunk-XOR swizzle (c ^ (r>>1)&3): linear gload_lds dest + pre-swizzled
// global source + same XOR on ds_read (rule 21).
// z=0: Q, terms (0,0),(0,1),(1,0),(1,1),(0,2),(2,0); z=1,2: first 3 terms.
// z=2 epilogue writes VT split-bf16 transposed [b,h][128][2048].
__global__ __launch_bounds__(256, 3) void gemm_proj(
    const u16* __restrict__ X1, const u16* __restrict__ X2, const u16* __restrict__ X3,
    const u16* __restrict__ W1, const u16* __restrict__ W2, const u16* __restrict__ W3,
    const float* __restrict__ bq, const float* __restrict__ bk, const float* __restrict__ bv,
    float* __restrict__ PROJ)
{
  int z = blockIdx.z;
  // T1: XCD-chunked swizzle within z (nwg=256, 8 XCDs, 32 per XCD).
  int orig = blockIdx.x + blockIdx.y * 8;          // 0..255
  int wg = (orig & 7) * 32 + (orig >> 3);          // bijective
  int bx = wg & 7, by = wg >> 3;                   // same-XCD blocks share 'by'

  const u16* Xa0 = X1 + (size_t)z * 4194304;
  const u16* Xa1 = X2 + (size_t)z * 4194304;
  const u16* Xa2 = X3;                       // only used when z==0
  const u16* Wb0 = W1 + (size_t)z * 1048576;
  const u16* Wb1 = W2 + (size_t)z * 1048576;
  const u16* Wb2 = W3;
  const float* bias = (z == 0) ? bq : (z == 1 ? bk : bv);
  float* C = PROJ + (size_t)z * 4194304;

  __shared__ __align__(16) u16 T[6 * 4096];  // 6 tiles of 128x32 u16 = 48 KB
  u16* A0t = T;          u16* A1t = T + 4096;  u16* A2t = T + 8192;
  u16* B0t = T + 12288;  u16* B1t = T + 16384; u16* B2t = T + 20480;

  int t = threadIdx.x;
  int wave = t >> 6, lane = t & 63;
  int wm = wave >> 1, wn = wave & 1;
  int lr = lane & 15, lk = lane >> 4;
  int rowA = by * 128, rowB = bx * 128;
  f32x4 acc[4][4] = {};
  bf16x8 af[4], bg[4];

#define STAGE(tile, G, R0)                                                    \
  {                                                                           \
    _Pragma("unroll")                                                         \
    for (int i = 0; i < 2; ++i){                                              \
      int p = i * 256 + t;                                                    \
      int r = p >> 2;                                                         \
      int c = (p & 3) ^ ((r >> 1) & 3);                                       \
      gload_lds16(G + (size_t)(R0 + r) * 1024 + pk + c * 8,                   \
                  &tile[(i * 256 + wave * 64) * 8]);                          \
    }                                                                         \
  }
#define LOAD_A(tile)                                                          \
  {                                                                           \
    _Pragma("unroll")                                                         \
    for (int m = 0; m < 4; ++m){                                              \
      int r = wm * 64 + m * 16 + lr;                                          \
      af[m] = *reinterpret_cast<const bf16x8*>(                               \
          &tile[r * 32 + ((lk ^ ((r >> 1) & 3)) << 3)]);                      \
    }                                                                         \
  }
#define LOAD_B(tile)                                                          \
  {                                                                           \
    _Pragma("unroll")                                                         \
    for (int n = 0; n < 4; ++n){                                              \
      int r = wn * 64 + n * 16 + lr;                                          \
      bg[n] = *reinterpret_cast<const bf16x8*>(                               \
          &tile[r * 32 + ((lk ^ ((r >> 1) & 3)) << 3)]);                      \
    }                                                                         \
  }
#define GRP()                                                                 \
  {                                                                           \
    _Pragma("unroll")                                                         \
    for (int m = 0; m < 4; ++m)                                               \
      _Pragma("unroll")                                                       \
      for (int n = 0; n < 4; ++n)                                             \
        acc[m][n] = __builtin_amdgcn_mfma_f32_16x16x32_bf16(af[m], bg[n],     \
                                                            acc[m][n], 0,0,0);\
  }

  for (int kt = 0; kt < 32; ++kt){
    int pk = kt * 32;
    STAGE(A0t, Xa0, rowA);
    STAGE(A1t, Xa1, rowA);
    STAGE(B0t, Wb0, rowB);
    STAGE(B1t, Wb1, rowB);
    if (z == 0){
      STAGE(A2t, Xa2, rowA);
      STAGE(B2t, Wb2, rowB);
    }
    __syncthreads();
    if (z == 0){
      LOAD_A(A0t); LOAD_B(B1t); GRP();   // (0,1)
      LOAD_A(A1t);              GRP();   // (1,1)
      LOAD_B(B0t);              GRP();   // (1,0)
      LOAD_A(A0t);              GRP();   // (0,0)
      LOAD_B(B2t);              GRP();   // (0,2)
      LOAD_A(A2t); LOAD_B(B0t); GRP();   // (2,0)
    } else {
      LOAD_A(A0t); LOAD_B(B1t); GRP();   // (0,1)
      LOAD_B(B0t);              GRP();   // (0,0)
      LOAD_A(A1t);              GRP();   // (1,0)
    }
    __syncthreads();
  }
#undef STAGE
#undef LOAD_A
#undef LOAD_B
#undef GRP

  if (z < 2){
#pragma unroll
    for (int m = 0; m < 4; ++m){
      int row0 = by * 128 + wm * 64 + m * 16 + (lane >> 4) * 4;
#pragma unroll
      for (int n = 0; n < 4; ++n){
        int col = bx * 128 + wn * 64 + n * 16 + (lane & 15);
        float bb = bias[col];
#pragma unroll
        for (int j = 0; j < 4; ++j)
          C[(size_t)(row0 + j) * 1024 + col] = acc[m][n][j] + bb;
      }
    }
  } else {
    u16* VT = (u16*)C;   // [32][128][2048] u16 (aliases PROJ z==2 slice)
#pragma unroll
    for (int m = 0; m < 4; ++m){
      int r0 = by * 128 + wm * 64 + m * 16 + (lane >> 4) * 4;
      int b = r0 >> 11, kb = r0 & 2047;
#pragma unroll
      for (int n = 0; n < 4; ++n){
        int c = bx * 128 + wn * 64 + n * 16 + (lane & 15);
        float bb = bias[c];
        int h = c >> 6, d = c & 63;
        u16 hi[4], lo[4];
#pragma unroll
        for (int j = 0; j < 4; ++j){
          float v = acc[m][n][j] + bb;
          hi[j] = f2bf(v);
          lo[j] = f2bf(v - bf2f(hi[j]));
        }
        size_t base = ((size_t)(b * 16 + h) * 128) * 2048 + (size_t)kb;
        *reinterpret_cast<ushort4*>(&VT[base + (size_t)d * 2048]) =
            make_ushort4(hi[0], hi[1], hi[2], hi[3]);
        *reinterpret_cast<ushort4*>(&VT[base + (size_t)(64 + d) * 2048]) =
            make_ushort4(lo[0], lo[1], lo[2], lo[3]);
      }
    }
  }
}

// ---------- K4: q_norm[b,h,l] = sum_d Q[b,l,h*64+d]^2 ----------
__global__ void qnorm_kernel(const float* __restrict__ PROJ, float* __restrict__ qn){
  int g = blockIdx.x * 256 + threadIdx.x;   // 65536
  int b = g >> 15, rem = g & 32767, h = rem >> 11, l = rem & 2047;
  const float* q = PROJ + (size_t)(b * 2048 + l) * 1024 + h * 64;
  float s = 0.f;
#pragma unroll 8
  for (int d = 0; d < 64; ++d){ float x = q[d]; s += x * x; }
  qn[(size_t)(b * 16 + h) * 2048 + l] = s;
}

// ---------- K5: iterative top-u argmax per (b,h); tie -> lower index ----------
__global__ void topk_kernel(const float* __restrict__ qn, int* __restrict__ topk,
                            unsigned char* __restrict__ seli, unsigned int* __restrict__ hmask,
                            const int* __restrict__ qvlp){
  int bh = blockIdx.x; int b = bh >> 4, h = bh & 15;
  int u = compute_u(qvlp[0]);
  __shared__ float v[2048];
  __shared__ float rv[256];
  __shared__ int ri[256];
  int t = threadIdx.x;
  for (int j = t; j < 2048; j += 256) v[j] = qn[(size_t)bh * 2048 + j];
  __syncthreads();
  for (int it = 0; it < u; ++it){
    float bvv = -3.4e38f; int bi = 2048;
    for (int j = t; j < 2048; j += 256){ float x = v[j]; if (x > bvv){ bvv = x; bi = j; } }
    rv[t] = bvv; ri[t] = bi;
    __syncthreads();
    for (int s = 128; s > 0; s >>= 1){
      if (t < s){
        if (rv[t+s] > rv[t] || (rv[t+s] == rv[t] && ri[t+s] < ri[t])){ rv[t] = rv[t+s]; ri[t] = ri[t+s]; }
      }
      __syncthreads();
    }
    if (t == 0){
      int idx = ri[0];
      topk[bh * 64 + it] = idx;
      seli[(size_t)bh * 2048 + idx] = (unsigned char)it;
      atomicOr(&hmask[b * 2048 + idx], 1u << h);
      v[idx] = -3.4e38f;
    }
    __syncthreads();
  }
}

// ---------- K6: scores for selected rows; bf16 round + bf16 mask add ----------
__global__ void scores_kernel(const float* __restrict__ PROJ, const int* __restrict__ topk,
                              const float* __restrict__ maskp, u16* __restrict__ sc,
                              const int* __restrict__ qvlp, const int* __restrict__ kvlp){
  int bh = blockIdx.y; int b = bh >> 4, h = bh & 15;
  int kvlv = kvlp[0]; if (kvlv > 2048) kvlv = 2048; if (kvlv < 0) kvlv = 0;
  int u = compute_u(qvlp[0]);
  int k0 = blockIdx.x * 128;
  if (k0 >= kvlv) return;
  int kcnt = kvlv - k0; if (kcnt > 128) kcnt = 128;
  int t = threadIdx.x;
  __shared__ int idx_l[64];
  __shared__ float qld[64 * 64];
  __shared__ float kld[128 * 65];
  const float* Q = PROJ;
  const float* K = PROJ + 4194304;
  if (t < u) idx_l[t] = topk[bh * 64 + t];
  __syncthreads();
  for (int e = t; e < u * 64; e += 256){
    int i = e >> 6, d = e & 63;
    qld[e] = Q[(size_t)(b * 2048 + idx_l[i]) * 1024 + h * 64 + d];
  }
  for (int e = t; e < 128 * 64; e += 256){
    int kk = e >> 6, d = e & 63;
    float vv = (kk < kcnt) ? K[(size_t)(b * 2048 + k0 + kk) * 1024 + h * 64 + d] : 0.f;
    kld[kk * 65 + d] = vv;
  }
  __syncthreads();
  for (int e = t; e < u * 128; e += 256){
    int i = e >> 7, kk = e & 127;
    if (kk >= kcnt) continue;
    const float* qr = &qld[i * 64];
    const float* kr = &kld[kk * 65];
    float s = 0.f;
#pragma unroll 8
    for (int d = 0; d < 64; ++d) s += qr[d] * kr[d];
    s *= 0.125f;                          // / sqrt(64)
    int l = idx_l[i]; int k = k0 + kk;
    u16 xb = f2bf(s);                     // scores.astype(bf16)
    u16 mb = f2bf(maskp[(size_t)l * 2048 + k]);   // attn_mask.astype(bf16) (kpm=0 here)
    u16 xm = f2bf(bf2f(xb) + bf2f(mb));   // bf16 add
    sc[(size_t)(bh * 64 + i) * 2048 + k] = xm;
  }
}

// ---------- K7: exact bf16 softmax emulation; p written in place ----------
__global__ void softmax_kernel(u16* __restrict__ sc, const int* __restrict__ qvlp,
                               const int* __restrict__ kvlp){
  int bh = blockIdx.y, i = blockIdx.x;
  int u = compute_u(qvlp[0]);
  if (i >= u) return;
  int kvlv = kvlp[0]; if (kvlv > 2048) kvlv = 2048; if (kvlv < 0) kvlv = 0;
  u16* row = sc + (size_t)(bh * 64 + i) * 2048;
  int t = threadIdx.x;
  float x[8];
  float lm = -3.4e38f;
#pragma unroll
  for (int j = 0; j < 8; ++j){
    int k = t + j * 256;
    x[j] = (k < kvlv) ? bf2f(row[k]) : -3.4e38f;
    lm = fmaxf(lm, x[j]);
  }
  __shared__ float red[256];
  red[t] = lm; __syncthreads();
  for (int s = 128; s > 0; s >>= 1){ if (t < s) red[t] = fmaxf(red[t], red[t+s]); __syncthreads(); }
  float m = red[0];
  __syncthreads();
  float e[8]; float ls = 0.f;
#pragma unroll
  for (int j = 0; j < 8; ++j){
    int k = t + j * 256;
    if (k < kvlv){
      u16 ub = f2bf(x[j] - m);            // bf16 subtract
      u16 eb = f2bf(expf(bf2f(ub)));      // bf16 exp
      e[j] = bf2f(eb);
      ls += e[j];
    } else e[j] = 0.f;
  }
  red[t] = ls; __syncthreads();
  for (int s = 128; s > 0; s >>= 1){ if (t < s) red[t] += red[t+s]; __syncthreads(); }
  float S = red[0];                       // f32 accumulation (jnp.sum upcast)
  float Sb = bf2f(f2bf(S));               // downcast back to bf16
#pragma unroll
  for (int j = 0; j < 8; ++j){
    int k = t + j * 256;
    if (k < 2048) row[k] = (k < kvlv) ? f2bf(e[j] / Sb) : (u16)0;   // bf16 divide
  }
}

// ---------- K8a: PV via MFMA, no LDS. part[kc][bh][64 rows][64 d] ----------
__global__ void pv_mfma(const u16* __restrict__ probs, const u16* __restrict__ VT,
                        float* __restrict__ part, const int* __restrict__ kvlp)
{
  int bh = blockIdx.y; int b = bh >> 4, h = bh & 15;
  int kvlv = kvlp[0]; if (kvlv > 2048) kvlv = 2048; if (kvlv < 0) kvlv = 0;
  int kc = blockIdx.x;
  int k0 = kc * 128;
  if (k0 >= kvlv) return;
  int t = threadIdx.x, w = t >> 6, lane = t & 63;
  int lr = lane & 15, lk = lane >> 4;
  const u16* Pb = probs + (size_t)bh * 64 * 2048;
  const u16* Vb = VT + (size_t)(b * 16 + h) * 128 * 2048;
  f32x4 acc[4] = {};
#pragma unroll
  for (int ks = 0; ks < 4; ++ks){
    int kk = k0 + ks * 32 + lk * 8;
    bf16x8 A0 = *reinterpret_cast<const bf16x8*>(Pb + (size_t)(lr     ) * 2048 + kk);
    bf16x8 A1 = *reinterpret_cast<const bf16x8*>(Pb + (size_t)(lr + 16) * 2048 + kk);
    bf16x8 A2 = *reinterpret_cast<const bf16x8*>(Pb + (size_t)(lr + 32) * 2048 + kk);
    bf16x8 A3 = *reinterpret_cast<const bf16x8*>(Pb + (size_t)(lr + 48) * 2048 + kk);
    bf16x8 Bh = *reinterpret_cast<const bf16x8*>(Vb + (size_t)(w * 16 + lr     ) * 2048 + kk);
    bf16x8 Bl = *reinterpret_cast<const bf16x8*>(Vb + (size_t)(w * 16 + lr + 64) * 2048 + kk);
    acc[0] = __builtin_amdgcn_mfma_f32_16x16x32_bf16(A0, Bh, acc[0], 0, 0, 0);
    acc[1] = __builtin_amdgcn_mfma_f32_16x16x32_bf16(A1, Bh, acc[1], 0, 0, 0);
    acc[2] = __builtin_amdgcn_mfma_f32_16x16x32_bf16(A2, Bh, acc[2], 0, 0, 0);
    acc[3] = __builtin_amdgcn_mfma_f32_16x16x32_bf16(A3, Bh, acc[3], 0, 0, 0);
    acc[0] = __builtin_amdgcn_mfma_f32_16x16x32_bf16(A0, Bl, acc[0], 0, 0, 0);
    acc[1] = __builtin_amdgcn_mfma_f32_16x16x32_bf16(A1, Bl, acc[1], 0, 0, 0);
    acc[2] = __builtin_amdgcn_mfma_f32_16x16x32_bf16(A2, Bl, acc[2], 0, 0, 0);
    acc[3] = __builtin_amdgcn_mfma_f32_16x16x32_bf16(A3, Bl, acc[3], 0, 0, 0);
  }
  float* pc = part + (size_t)(kc * 32 + bh) * 64 * 64;
#pragma unroll
  for (int m = 0; m < 4; ++m){
    int row = m * 16 + lk * 4;
#pragma unroll
    for (int j = 0; j < 4; ++j)
      pc[(size_t)(row + j) * 64 + w * 16 + lr] = acc[m][j];
  }
}

// ---------- K8b: deterministic reduction of PV partials ----------
__global__ void pv_reduce(const float* __restrict__ part, float* __restrict__ ctx,
                          const int* __restrict__ qvlp, const int* __restrict__ kvlp){
  int bh = blockIdx.y, r = blockIdx.x;
  int u = compute_u(qvlp[0]);
  if (r >= u) return;
  int kvlv = kvlp[0]; if (kvlv > 2048) kvlv = 2048; if (kvlv < 0) kvlv = 0;
  int kcmax = (kvlv + 127) / 128;
  int d = threadIdx.x;   // 64
  float s = 0.f;
  for (int kc = 0; kc < kcmax; ++kc)
    s += part[(size_t)((kc * 32 + bh) * 64 + r) * 64 + d];
  ctx[(size_t)(bh * 64 + r) * 64 + d] = s;
}

// ---------- K9: sparse output projection; unselected rows = bo ----------
__global__ void outproj_kernel(const float* __restrict__ ctx, const float* __restrict__ WoT,
                               const float* __restrict__ bo, const unsigned int* __restrict__ hmask,
                               const unsigned char* __restrict__ seli, float* __restrict__ out){
  int row = blockIdx.x;                 // b*2048 + l
  int b = row >> 11, l = row & 2047;
  int t = threadIdx.x;
  float acc[4];
#pragma unroll
  for (int r = 0; r < 4; ++r) acc[r] = bo[t + r * 256];
  unsigned int m = hmask[row];
  __shared__ float clds[64];
  while (m){
    int h = __ffs(m) - 1; m &= (m - 1);
    int i = (int)seli[(size_t)(b * 16 + h) * 2048 + l];
    __syncthreads();
    if (t < 64) clds[t] = ctx[(size_t)((b * 16 + h) * 64 + i) * 64 + t];
    __syncthreads();
    for (int j = 0; j < 64; ++j){
      float c = clds[j];
      const float* wrow = &WoT[(size_t)(h * 64 + j) * 1024];
#pragma unroll
      for (int r = 0; r < 4; ++r) acc[r] += c * wrow[t + r * 256];
    }
  }
  float* orow = out + (size_t)row * 1024;
#pragma unroll
  for (int r = 0; r < 4; ++r) orow[t + r * 256] = acc[r];
}

__global__ void fail_fill(float* o, int n){
  int i = blockIdx.x * 256 + threadIdx.x;
  if (i < n) o[i] = 12345.0f;
}

// ---------------------------------------------------------------------------
extern "C" void kernel_launch(void* const* d_in, const int* in_sizes, int n_in,
                              void* d_out, int out_size, void* d_ws, size_t ws_size,
                              hipStream_t stream)
{
  const float* query = (const float*)d_in[0];
  const float* key   = (const float*)d_in[1];
  const float* value = (const float*)d_in[2];
  const float* maskp = (const float*)d_in[3];
  const float* Wq = (const float*)d_in[4];
  const float* bq = (const float*)d_in[5];
  const float* Wk = (const float*)d_in[6];
  const float* bk = (const float*)d_in[7];
  const float* Wv = (const float*)d_in[8];
  const float* bv = (const float*)d_in[9];
  const float* Wo = (const float*)d_in[10];
  const float* bo = (const float*)d_in[11];
  const int* qvl = (const int*)d_in[12];
  const int* kvl = (const int*)d_in[13];
  float* out = (float*)d_out;

  char* ws = (char*)d_ws;
  size_t off = 0;
  auto alloc = [&](size_t bytes) -> void* {
    void* p = ws + off;
    off = (off + bytes + 255) & ~(size_t)255;
    return p;
  };
  u16* X1 = (u16*)alloc(3ull * 4194304 * 2);
  u16* X2 = (u16*)alloc(3ull * 4194304 * 2);
  u16* X3 = (u16*)alloc(1ull * 4194304 * 2);
  u16* W1 = (u16*)alloc(3ull * 1048576 * 2);
  u16* W2 = (u16*)alloc(3ull * 1048576 * 2);
  u16* W3 = (u16*)alloc(1ull * 1048576 * 2);
  float* PROJ = (float*)alloc(3ull * 4194304 * 4);
  float* WOT  = (float*)alloc(4194304ull);
  float* QN   = (float*)alloc(2ull * 16 * 2048 * 4);
  int*   TOPK = (int*)alloc(2ull * 16 * 64 * 4);
  unsigned char* SELI = (unsigned char*)alloc(2ull * 16 * 2048);
  unsigned int* HMASK = (unsigned int*)alloc(2ull * 2048 * 4);
  u16*   SC   = (u16*)alloc(2048ull * 2048 * 2);
  float* CTX  = (float*)alloc(2048ull * 64 * 4);

  // VT (split-bf16 transposed V) aliases the PROJ z==2 slice (exactly 16.78 MB)
  u16* VT = (u16*)(PROJ + 2ull * 4194304);
  // PV partials alias X1 (24 MB, dead after gemm_proj): 16*32*64*64*4 = 8.4 MB
  float* PART = (float*)X1;

  if (ws_size < off){
    fail_fill<<<(out_size + 255) / 256, 256, 0, stream>>>(out, out_size);
    return;
  }

  hipMemsetAsync(SELI, 0xFF, 2ull * 16 * 2048, stream);
  hipMemsetAsync(HMASK, 0, 2ull * 2048 * 4, stream);

  expand_kernel<<<15360, 256, 0, stream>>>(query, key, value, Wq, Wk, Wv,
                                           X1, X2, X3, W1, W2, W3);
  wot_kernel<<<dim3(32, 32), dim3(32, 8), 0, stream>>>(Wo, WOT);
  gemm_proj<<<dim3(8, 32, 3), 256, 0, stream>>>(X1, X2, X3, W1, W2, W3, bq, bk, bv, PROJ);
  qnorm_kernel<<<256, 256, 0, stream>>>(PROJ, QN);
  topk_kernel<<<32, 256, 0, stream>>>(QN, TOPK, SELI, HMASK, qvl);
  scores_kernel<<<dim3(16, 32), 256, 0, stream>>>(PROJ, TOPK, maskp, SC, qvl, kvl);
  softmax_kernel<<<dim3(64, 32), 256, 0, stream>>>(SC, qvl, kvl);
  pv_mfma<<<dim3(16, 32), 256, 0, stream>>>(SC, VT, PART, kvl);
  pv_reduce<<<dim3(64, 32), 64, 0, stream>>>(PART, CTX, qvl, kvl);
  outproj_kernel<<<4096, 256, 0, stream>>>(CTX, WOT, bo, HMASK, SELI, out);
}

// Round 5
// 280.868 us; speedup vs baseline: 2.5318x; 1.1546x over previous
//
#include <hip/hip_runtime.h>

typedef unsigned short u16;
typedef __bf16 bf16x8 __attribute__((ext_vector_type(8)));
typedef float f32x4 __attribute__((ext_vector_type(4)));

// ---------- numeric helpers (RNE f32<->bf16, matching XLA/ml_dtypes) ----------
__device__ __forceinline__ u16 f2bf(float f){
  unsigned int x = __float_as_uint(f);
  unsigned int r = (x + 0x7FFFu + ((x >> 16) & 1u)) >> 16;
  return (u16)r;
}
__device__ __forceinline__ float bf2f(u16 u){
  return __uint_as_float(((unsigned int)u) << 16);
}
__device__ __forceinline__ int compute_u(int qvlv){
  int mm = qvlv > 2 ? qvlv : 2;
  int u = (int)(5.0 * log((double)mm));   // FACTOR=5.0, python int() truncation
  if (u < 1) u = 1;
  if (u > 64) u = 64;
  return u;
}
__device__ __forceinline__ void gload_lds16(const void* g, void* l){
  __builtin_amdgcn_global_load_lds(
      (const __attribute__((address_space(1))) void*)g,
      (__attribute__((address_space(3))) void*)l, 16, 0, 0);
}

// ---------- K1: split f32 -> 3 bf16 levels (X for q/k/v, W for Wq/Wk/Wv) ----------
__global__ void expand_kernel(const float* __restrict__ xq, const float* __restrict__ xk,
                              const float* __restrict__ xv,
                              const float* __restrict__ wq, const float* __restrict__ wk,
                              const float* __restrict__ wv,
                              u16* __restrict__ X1, u16* __restrict__ X2, u16* __restrict__ X3,
                              u16* __restrict__ W1, u16* __restrict__ W2, u16* __restrict__ W3)
{
  size_t g = (size_t)blockIdx.x * 256 + threadIdx.x;  // one group = 4 floats
  const float* src; u16 *d1, *d2, *d3;
  if (g < 3145728ull) {                 // X part: 3 * 4194304 / 4
    int p = (int)(g >> 20);
    size_t e = (g & 1048575ull) * 4;
    src = (p == 0 ? xq : (p == 1 ? xk : xv)) + e;
    size_t o = (size_t)p * 4194304ull + e;
    d1 = X1 + o; d2 = X2 + o; d3 = (p == 0) ? (X3 + e) : (u16*)0;
  } else {                              // W part: 3 * 1048576 / 4
    size_t wg = g - 3145728ull;
    int p = (int)(wg >> 18);
    size_t e = (wg & 262143ull) * 4;
    src = (p == 0 ? wq : (p == 1 ? wk : wv)) + e;
    size_t o = (size_t)p * 1048576ull + e;
    d1 = W1 + o; d2 = W2 + o; d3 = (p == 0) ? (W3 + e) : (u16*)0;
  }
  float4 x = *reinterpret_cast<const float4*>(src);
  float xs[4] = {x.x, x.y, x.z, x.w};
  u16 h1[4], h2[4], h3[4];
#pragma unroll
  for (int i = 0; i < 4; ++i){
    float v = xs[i];
    u16 a = f2bf(v);  float r1 = v  - bf2f(a);
    u16 b = f2bf(r1); float r2 = r1 - bf2f(b);
    u16 c = f2bf(r2);
    h1[i] = a; h2[i] = b; h3[i] = c;
  }
  *reinterpret_cast<ushort4*>(d1) = make_ushort4(h1[0], h1[1], h1[2], h1[3]);
  *reinterpret_cast<ushort4*>(d2) = make_ushort4(h2[0], h2[1], h2[2], h2[3]);
  if (d3) *reinterpret_cast<ushort4*>(d3) = make_ushort4(h3[0], h3[1], h3[2], h3[3]);
}

// ---------- K2: WoT[j][d] = Wo[d][j] ----------
__global__ void wot_kernel(const float* __restrict__ Wo, float* __restrict__ WoT){
  __shared__ float tile[32][33];
  int tx = threadIdx.x, ty = threadIdx.y;   // 32 x 8
  int bx = blockIdx.x * 32, by = blockIdx.y * 32;
#pragma unroll
  for (int r = 0; r < 4; ++r)
    tile[ty + r*8][tx] = Wo[(size_t)(by + ty + r*8) * 1024 + bx + tx];
  __syncthreads();
#pragma unroll
  for (int r = 0; r < 4; ++r)
    WoT[(size_t)(bx + ty + r*8) * 1024 + by + tx] = tile[tx][ty + r*8];
}

// ---------- K3: split-precision bf16 MFMA GEMM  C = X @ W^T + bias ----------
// 8 waves, BM=256 BN=128 BK=32, double-buffered term-shared tile sets,
// one barrier per K-chunk, stage-issue before compute (latency hidden under
// 96/48 MFMAs), alternating frag register sets, setprio around MFMA.
// z=0: Q terms {A0B0,A0B1,A1B0,A1B1,A0B2,A2B0}; z>=1: {A0B0,A0B1,A1B0}.
// z=2 epilogue writes VT split-bf16 transposed [b,h][128][2048].
__global__ __launch_bounds__(512, 1) void gemm_proj(
    const u16* __restrict__ X1, const u16* __restrict__ X2, const u16* __restrict__ X3,
    const u16* __restrict__ W1, const u16* __restrict__ W2, const u16* __restrict__ W3,
    const float* __restrict__ bq, const float* __restrict__ bk, const float* __restrict__ bv,
    float* __restrict__ PROJ)
{
  int z = blockIdx.z;
  // XCD-chunked bijective swizzle: 128 blocks/z, 8 XCDs, 16 per XCD
  int orig = blockIdx.x + blockIdx.y * 8;          // 0..127
  int wgid = (orig & 7) * 16 + (orig >> 3);
  int bx = wgid & 7, by = wgid >> 3;               // same-XCD blocks share by-panels

  const u16* Xa0 = X1 + (size_t)z * 4194304;
  const u16* Xa1 = X2 + (size_t)z * 4194304;
  const u16* Xa2 = X3;                       // only used when z==0
  const u16* Wb0 = W1 + (size_t)z * 1048576;
  const u16* Wb1 = W2 + (size_t)z * 1048576;
  const u16* Wb2 = W3;
  const float* bias = (z == 0) ? bq : (z == 1 ? bk : bv);
  float* C = PROJ + (size_t)z * 4194304;

  // dbuf tile sets: per set A0[256][32],A1,A2 (8192 u16 each) + B0[128][32],B1,B2 (4096)
  __shared__ __align__(16) u16 T[2 * 36864];       // 144 KB
  u16* SET0 = T;
  u16* SET1 = T + 36864;

  int t = threadIdx.x;
  int wave = t >> 6, lane = t & 63;
  int wm = wave >> 1, wn = wave & 1;               // 4 x 2 wave grid
  int lr = lane & 15, lk = lane >> 4;
  int rowA = by * 256, rowB = bx * 128;
  f32x4 acc[4][4] = {};
  bf16x8 afA[4], afB[4], bgA[4], bgB[4];

#define STAGEA(dstbase, G)                                                    \
  {                                                                           \
    _Pragma("unroll")                                                         \
    for (int i = 0; i < 2; ++i){                                              \
      int p = i * 512 + t;                                                    \
      int r = p >> 2;                                                         \
      int c = (p & 3) ^ ((r >> 1) & 3);                                       \
      gload_lds16(G + (size_t)(rowA + r) * 1024 + pk + c * 8,                 \
                  (dstbase) + p * 8);                                         \
    }                                                                         \
  }
#define STAGEB(dstbase, G)                                                    \
  {                                                                           \
    int p = t;                                                                \
    int r = p >> 2;                                                           \
    int c = (p & 3) ^ ((r >> 1) & 3);                                         \
    gload_lds16(G + (size_t)(rowB + r) * 1024 + pk + c * 8,                   \
                (dstbase) + p * 8);                                           \
  }
#define STAGE_SET(S)                                                          \
  {                                                                           \
    STAGEA((S), Xa0); STAGEA((S) + 8192, Xa1);                                \
    STAGEB((S) + 24576, Wb0); STAGEB((S) + 28672, Wb1);                       \
    if (z == 0){ STAGEA((S) + 16384, Xa2); STAGEB((S) + 32768, Wb2); }        \
  }
#define LOADA(dst, tile)                                                      \
  {                                                                           \
    _Pragma("unroll")                                                         \
    for (int m = 0; m < 4; ++m){                                              \
      int r = wm * 64 + m * 16 + lr;                                          \
      dst[m] = *reinterpret_cast<const bf16x8*>(                              \
          &(tile)[r * 32 + ((lk ^ ((r >> 1) & 3)) << 3)]);                    \
    }                                                                         \
  }
#define LOADB(dst, tile)                                                      \
  {                                                                           \
    _Pragma("unroll")                                                         \
    for (int n = 0; n < 4; ++n){                                              \
      int r = wn * 64 + n * 16 + lr;                                          \
      dst[n] = *reinterpret_cast<const bf16x8*>(                              \
          &(tile)[r * 32 + ((lk ^ ((r >> 1) & 3)) << 3)]);                    \
    }                                                                         \
  }
#define GRPX(A_, B_)                                                          \
  {                                                                           \
    __builtin_amdgcn_s_setprio(1);                                            \
    _Pragma("unroll")                                                         \
    for (int m = 0; m < 4; ++m)                                               \
      _Pragma("unroll")                                                       \
      for (int n = 0; n < 4; ++n)                                             \
        acc[m][n] = __builtin_amdgcn_mfma_f32_16x16x32_bf16(A_[m], B_[n],     \
                                                            acc[m][n], 0,0,0);\
    __builtin_amdgcn_s_setprio(0);                                            \
  }

  {                                    // prologue: stage chunk 0
    int pk = 0;
    STAGE_SET(SET0);
  }
  __syncthreads();

  for (int kt = 0; kt < 32; ++kt){
    u16* CUR = (kt & 1) ? SET1 : SET0;
    u16* NXT = (kt & 1) ? SET0 : SET1;
    if (kt < 31){
      int pk = (kt + 1) * 32;
      STAGE_SET(NXT);                  // issue next-chunk loads (hidden under MFMA)
    }
    __builtin_amdgcn_sched_barrier(0); // keep stage-issue ahead of compute
    u16* A0t = CUR;          u16* A1t = CUR + 8192;  u16* A2t = CUR + 16384;
    u16* B0t = CUR + 24576;  u16* B1t = CUR + 28672; u16* B2t = CUR + 32768;
    if (z == 0){
      LOADA(afA, A0t); LOADB(bgA, B1t);
      LOADA(afB, A1t); GRPX(afA, bgA);   // A0*B1
      LOADB(bgB, B0t); GRPX(afB, bgA);   // A1*B1
      LOADA(afA, A0t); GRPX(afB, bgB);   // A1*B0
      LOADB(bgA, B2t); GRPX(afA, bgB);   // A0*B0
      LOADA(afB, A2t); GRPX(afA, bgA);   // A0*B2
                       GRPX(afB, bgB);   // A2*B0
    } else {
      LOADA(afA, A0t); LOADB(bgA, B0t);
      LOADB(bgB, B1t); GRPX(afA, bgA);   // A0*B0
      LOADA(afB, A1t); GRPX(afA, bgB);   // A0*B1
                       GRPX(afB, bgA);   // A1*B0
    }
    __syncthreads();                   // drains vmcnt: next chunk staged & visible
  }
#undef STAGEA
#undef STAGEB
#undef STAGE_SET
#undef LOADA
#undef LOADB
#undef GRPX

  if (z < 2){
#pragma unroll
    for (int m = 0; m < 4; ++m){
      int row0 = by * 256 + wm * 64 + m * 16 + (lane >> 4) * 4;
#pragma unroll
      for (int n = 0; n < 4; ++n){
        int col = bx * 128 + wn * 64 + n * 16 + (lane & 15);
        float bb = bias[col];
#pragma unroll
        for (int j = 0; j < 4; ++j)
          C[(size_t)(row0 + j) * 1024 + col] = acc[m][n][j] + bb;
      }
    }
  } else {
    u16* VT = (u16*)C;   // [32][128][2048] u16 (aliases PROJ z==2 slice)
#pragma unroll
    for (int m = 0; m < 4; ++m){
      int r0 = by * 256 + wm * 64 + m * 16 + (lane >> 4) * 4;
      int b = r0 >> 11, kb = r0 & 2047;
#pragma unroll
      for (int n = 0; n < 4; ++n){
        int c = bx * 128 + wn * 64 + n * 16 + (lane & 15);
        float bb = bias[c];
        int h = c >> 6, d = c & 63;
        u16 hi[4], lo[4];
#pragma unroll
        for (int j = 0; j < 4; ++j){
          float v = acc[m][n][j] + bb;
          hi[j] = f2bf(v);
          lo[j] = f2bf(v - bf2f(hi[j]));
        }
        size_t base = ((size_t)(b * 16 + h) * 128) * 2048 + (size_t)kb;
        *reinterpret_cast<ushort4*>(&VT[base + (size_t)d * 2048]) =
            make_ushort4(hi[0], hi[1], hi[2], hi[3]);
        *reinterpret_cast<ushort4*>(&VT[base + (size_t)(64 + d) * 2048]) =
            make_ushort4(lo[0], lo[1], lo[2], lo[3]);
      }
    }
  }
}

// ---------- K4: q_norm[b,h,l] = sum_d Q[b,l,h*64+d]^2 ----------
__global__ void qnorm_kernel(const float* __restrict__ PROJ, float* __restrict__ qn){
  int g = blockIdx.x * 256 + threadIdx.x;   // 65536
  int b = g >> 15, rem = g & 32767, h = rem >> 11, l = rem & 2047;
  const float* q = PROJ + (size_t)(b * 2048 + l) * 1024 + h * 64;
  float s = 0.f;
#pragma unroll 8
  for (int d = 0; d < 64; ++d){ float x = q[d]; s += x * x; }
  qn[(size_t)(b * 16 + h) * 2048 + l] = s;
}

// ---------- K5: iterative top-u argmax per (b,h); tie -> lower index ----------
__global__ void topk_kernel(const float* __restrict__ qn, int* __restrict__ topk,
                            unsigned char* __restrict__ seli, unsigned int* __restrict__ hmask,
                            const int* __restrict__ qvlp){
  int bh = blockIdx.x; int b = bh >> 4, h = bh & 15;
  int u = compute_u(qvlp[0]);
  __shared__ float v[2048];
  __shared__ float rv[256];
  __shared__ int ri[256];
  int t = threadIdx.x;
  for (int j = t; j < 2048; j += 256) v[j] = qn[(size_t)bh * 2048 + j];
  __syncthreads();
  for (int it = 0; it < u; ++it){
    float bvv = -3.4e38f; int bi = 2048;
    for (int j = t; j < 2048; j += 256){ float x = v[j]; if (x > bvv){ bvv = x; bi = j; } }
    rv[t] = bvv; ri[t] = bi;
    __syncthreads();
    for (int s = 128; s > 0; s >>= 1){
      if (t < s){
        if (rv[t+s] > rv[t] || (rv[t+s] == rv[t] && ri[t+s] < ri[t])){ rv[t] = rv[t+s]; ri[t] = ri[t+s]; }
      }
      __syncthreads();
    }
    if (t == 0){
      int idx = ri[0];
      topk[bh * 64 + it] = idx;
      seli[(size_t)bh * 2048 + idx] = (unsigned char)it;
      atomicOr(&hmask[b * 2048 + idx], 1u << h);
      v[idx] = -3.4e38f;
    }
    __syncthreads();
  }
}

// ---------- K6: scores for selected rows; bf16 round + bf16 mask add ----------
__global__ void scores_kernel(const float* __restrict__ PROJ, const int* __restrict__ topk,
                              const float* __restrict__ maskp, u16* __restrict__ sc,
                              const int* __restrict__ qvlp, const int* __restrict__ kvlp){
  int bh = blockIdx.y; int b = bh >> 4, h = bh & 15;
  int kvlv = kvlp[0]; if (kvlv > 2048) kvlv = 2048; if (kvlv < 0) kvlv = 0;
  int u = compute_u(qvlp[0]);
  int k0 = blockIdx.x * 128;
  if (k0 >= kvlv) return;
  int kcnt = kvlv - k0; if (kcnt > 128) kcnt = 128;
  int t = threadIdx.x;
  __shared__ int idx_l[64];
  __shared__ float qld[64 * 64];
  __shared__ float kld[128 * 65];
  const float* Q = PROJ;
  const float* K = PROJ + 4194304;
  if (t < u) idx_l[t] = topk[bh * 64 + t];
  __syncthreads();
  for (int e = t; e < u * 64; e += 256){
    int i = e >> 6, d = e & 63;
    qld[e] = Q[(size_t)(b * 2048 + idx_l[i]) * 1024 + h * 64 + d];
  }
  for (int e = t; e < 128 * 64; e += 256){
    int kk = e >> 6, d = e & 63;
    float vv = (kk < kcnt) ? K[(size_t)(b * 2048 + k0 + kk) * 1024 + h * 64 + d] : 0.f;
    kld[kk * 65 + d] = vv;
  }
  __syncthreads();
  for (int e = t; e < u * 128; e += 256){
    int i = e >> 7, kk = e & 127;
    if (kk >= kcnt) continue;
    const float* qr = &qld[i * 64];
    const float* kr = &kld[kk * 65];
    float s = 0.f;
#pragma unroll 8
    for (int d = 0; d < 64; ++d) s += qr[d] * kr[d];
    s *= 0.125f;                          // / sqrt(64)
    int l = idx_l[i]; int k = k0 + kk;
    u16 xb = f2bf(s);                     // scores.astype(bf16)
    u16 mb = f2bf(maskp[(size_t)l * 2048 + k]);   // attn_mask.astype(bf16) (kpm=0 here)
    u16 xm = f2bf(bf2f(xb) + bf2f(mb));   // bf16 add
    sc[(size_t)(bh * 64 + i) * 2048 + k] = xm;
  }
}

// ---------- K7: exact bf16 softmax emulation; p written in place ----------
__global__ void softmax_kernel(u16* __restrict__ sc, const int* __restrict__ qvlp,
                               const int* __restrict__ kvlp){
  int bh = blockIdx.y, i = blockIdx.x;
  int u = compute_u(qvlp[0]);
  if (i >= u) return;
  int kvlv = kvlp[0]; if (kvlv > 2048) kvlv = 2048; if (kvlv < 0) kvlv = 0;
  u16* row = sc + (size_t)(bh * 64 + i) * 2048;
  int t = threadIdx.x;
  float x[8];
  float lm = -3.4e38f;
#pragma unroll
  for (int j = 0; j < 8; ++j){
    int k = t + j * 256;
    x[j] = (k < kvlv) ? bf2f(row[k]) : -3.4e38f;
    lm = fmaxf(lm, x[j]);
  }
  __shared__ float red[256];
  red[t] = lm; __syncthreads();
  for (int s = 128; s > 0; s >>= 1){ if (t < s) red[t] = fmaxf(red[t], red[t+s]); __syncthreads(); }
  float m = red[0];
  __syncthreads();
  float e[8]; float ls = 0.f;
#pragma unroll
  for (int j = 0; j < 8; ++j){
    int k = t + j * 256;
    if (k < kvlv){
      u16 ub = f2bf(x[j] - m);            // bf16 subtract
      u16 eb = f2bf(expf(bf2f(ub)));      // bf16 exp
      e[j] = bf2f(eb);
      ls += e[j];
    } else e[j] = 0.f;
  }
  red[t] = ls; __syncthreads();
  for (int s = 128; s > 0; s >>= 1){ if (t < s) red[t] += red[t+s]; __syncthreads(); }
  float S = red[0];                       // f32 accumulation (jnp.sum upcast)
  float Sb = bf2f(f2bf(S));               // downcast back to bf16
#pragma unroll
  for (int j = 0; j < 8; ++j){
    int k = t + j * 256;
    if (k < 2048) row[k] = (k < kvlv) ? f2bf(e[j] / Sb) : (u16)0;   // bf16 divide
  }
}

// ---------- K8a: PV via MFMA, no LDS. part[kc][bh][64 rows][64 d] ----------
__global__ void pv_mfma(const u16* __restrict__ probs, const u16* __restrict__ VT,
                        float* __restrict__ part, const int* __restrict__ kvlp)
{
  int bh = blockIdx.y; int b = bh >> 4, h = bh & 15;
  int kvlv = kvlp[0]; if (kvlv > 2048) kvlv = 2048; if (kvlv < 0) kvlv = 0;
  int kc = blockIdx.x;
  int k0 = kc * 128;
  if (k0 >= kvlv) return;
  int t = threadIdx.x, w = t >> 6, lane = t & 63;
  int lr = lane & 15, lk = lane >> 4;
  const u16* Pb = probs + (size_t)bh * 64 * 2048;
  const u16* Vb = VT + (size_t)(b * 16 + h) * 128 * 2048;
  f32x4 acc[4] = {};
#pragma unroll
  for (int ks = 0; ks < 4; ++ks){
    int kk = k0 + ks * 32 + lk * 8;
    bf16x8 A0 = *reinterpret_cast<const bf16x8*>(Pb + (size_t)(lr     ) * 2048 + kk);
    bf16x8 A1 = *reinterpret_cast<const bf16x8*>(Pb + (size_t)(lr + 16) * 2048 + kk);
    bf16x8 A2 = *reinterpret_cast<const bf16x8*>(Pb + (size_t)(lr + 32) * 2048 + kk);
    bf16x8 A3 = *reinterpret_cast<const bf16x8*>(Pb + (size_t)(lr + 48) * 2048 + kk);
    bf16x8 Bh = *reinterpret_cast<const bf16x8*>(Vb + (size_t)(w * 16 + lr     ) * 2048 + kk);
    bf16x8 Bl = *reinterpret_cast<const bf16x8*>(Vb + (size_t)(w * 16 + lr + 64) * 2048 + kk);
    acc[0] = __builtin_amdgcn_mfma_f32_16x16x32_bf16(A0, Bh, acc[0], 0, 0, 0);
    acc[1] = __builtin_amdgcn_mfma_f32_16x16x32_bf16(A1, Bh, acc[1], 0, 0, 0);
    acc[2] = __builtin_amdgcn_mfma_f32_16x16x32_bf16(A2, Bh, acc[2], 0, 0, 0);
    acc[3] = __builtin_amdgcn_mfma_f32_16x16x32_bf16(A3, Bh, acc[3], 0, 0, 0);
    acc[0] = __builtin_amdgcn_mfma_f32_16x16x32_bf16(A0, Bl, acc[0], 0, 0, 0);
    acc[1] = __builtin_amdgcn_mfma_f32_16x16x32_bf16(A1, Bl, acc[1], 0, 0, 0);
    acc[2] = __builtin_amdgcn_mfma_f32_16x16x32_bf16(A2, Bl, acc[2], 0, 0, 0);
    acc[3] = __builtin_amdgcn_mfma_f32_16x16x32_bf16(A3, Bl, acc[3], 0, 0, 0);
  }
  float* pc = part + (size_t)(kc * 32 + bh) * 64 * 64;
#pragma unroll
  for (int m = 0; m < 4; ++m){
    int row = m * 16 + lk * 4;
#pragma unroll
    for (int j = 0; j < 4; ++j)
      pc[(size_t)(row + j) * 64 + w * 16 + lr] = acc[m][j];
  }
}

// ---------- K8b: deterministic reduction of PV partials ----------
__global__ void pv_reduce(const float* __restrict__ part, float* __restrict__ ctx,
                          const int* __restrict__ qvlp, const int* __restrict__ kvlp){
  int bh = blockIdx.y, r = blockIdx.x;
  int u = compute_u(qvlp[0]);
  if (r >= u) return;
  int kvlv = kvlp[0]; if (kvlv > 2048) kvlv = 2048; if (kvlv < 0) kvlv = 0;
  int kcmax = (kvlv + 127) / 128;
  int d = threadIdx.x;   // 64
  float s = 0.f;
  for (int kc = 0; kc < kcmax; ++kc)
    s += part[(size_t)((kc * 32 + bh) * 64 + r) * 64 + d];
  ctx[(size_t)(bh * 64 + r) * 64 + d] = s;
}

// ---------- K9: sparse output projection; unselected rows = bo ----------
__global__ void outproj_kernel(const float* __restrict__ ctx, const float* __restrict__ WoT,
                               const float* __restrict__ bo, const unsigned int* __restrict__ hmask,
                               const unsigned char* __restrict__ seli, float* __restrict__ out){
  int row = blockIdx.x;                 // b*2048 + l
  int b = row >> 11, l = row & 2047;
  int t = threadIdx.x;
  float acc[4];
#pragma unroll
  for (int r = 0; r < 4; ++r) acc[r] = bo[t + r * 256];
  unsigned int m = hmask[row];
  __shared__ float clds[64];
  while (m){
    int h = __ffs(m) - 1; m &= (m - 1);
    int i = (int)seli[(size_t)(b * 16 + h) * 2048 + l];
    __syncthreads();
    if (t < 64) clds[t] = ctx[(size_t)((b * 16 + h) * 64 + i) * 64 + t];
    __syncthreads();
    for (int j = 0; j < 64; ++j){
      float c = clds[j];
      const float* wrow = &WoT[(size_t)(h * 64 + j) * 1024];
#pragma unroll
      for (int r = 0; r < 4; ++r) acc[r] += c * wrow[t + r * 256];
    }
  }
  float* orow = out + (size_t)row * 1024;
#pragma unroll
  for (int r = 0; r < 4; ++r) orow[t + r * 256] = acc[r];
}

__global__ void fail_fill(float* o, int n){
  int i = blockIdx.x * 256 + threadIdx.x;
  if (i < n) o[i] = 12345.0f;
}

// ---------------------------------------------------------------------------
extern "C" void kernel_launch(void* const* d_in, const int* in_sizes, int n_in,
                              void* d_out, int out_size, void* d_ws, size_t ws_size,
                              hipStream_t stream)
{
  const float* query = (const float*)d_in[0];
  const float* key   = (const float*)d_in[1];
  const float* value = (const float*)d_in[2];
  const float* maskp = (const float*)d_in[3];
  const float* Wq = (const float*)d_in[4];
  const float* bq = (const float*)d_in[5];
  const float* Wk = (const float*)d_in[6];
  const float* bk = (const float*)d_in[7];
  const float* Wv = (const float*)d_in[8];
  const float* bv = (const float*)d_in[9];
  const float* Wo = (const float*)d_in[10];
  const float* bo = (const float*)d_in[11];
  const int* qvl = (const int*)d_in[12];
  const int* kvl = (const int*)d_in[13];
  float* out = (float*)d_out;

  char* ws = (char*)d_ws;
  size_t off = 0;
  auto alloc = [&](size_t bytes) -> void* {
    void* p = ws + off;
    off = (off + bytes + 255) & ~(size_t)255;
    return p;
  };
  u16* X1 = (u16*)alloc(3ull * 4194304 * 2);
  u16* X2 = (u16*)alloc(3ull * 4194304 * 2);
  u16* X3 = (u16*)alloc(1ull * 4194304 * 2);
  u16* W1 = (u16*)alloc(3ull * 1048576 * 2);
  u16* W2 = (u16*)alloc(3ull * 1048576 * 2);
  u16* W3 = (u16*)alloc(1ull * 1048576 * 2);
  float* PROJ = (float*)alloc(3ull * 4194304 * 4);
  float* WOT  = (float*)alloc(4194304ull);
  float* QN   = (float*)alloc(2ull * 16 * 2048 * 4);
  int*   TOPK = (int*)alloc(2ull * 16 * 64 * 4);
  unsigned char* SELI = (unsigned char*)alloc(2ull * 16 * 2048);
  unsigned int* HMASK = (unsigned int*)alloc(2ull * 2048 * 4);
  u16*   SC   = (u16*)alloc(2048ull * 2048 * 2);
  float* CTX  = (float*)alloc(2048ull * 64 * 4);

  // VT (split-bf16 transposed V) aliases the PROJ z==2 slice (exactly 16.78 MB)
  u16* VT = (u16*)(PROJ + 2ull * 4194304);
  // PV partials alias X1 (24 MB, dead after gemm_proj): 16*32*64*64*4 = 8.4 MB
  float* PART = (float*)X1;

  if (ws_size < off){
    fail_fill<<<(out_size + 255) / 256, 256, 0, stream>>>(out, out_size);
    return;
  }

  hipMemsetAsync(SELI, 0xFF, 2ull * 16 * 2048, stream);
  hipMemsetAsync(HMASK, 0, 2ull * 2048 * 4, stream);

  expand_kernel<<<15360, 256, 0, stream>>>(query, key, value, Wq, Wk, Wv,
                                           X1, X2, X3, W1, W2, W3);
  wot_kernel<<<dim3(32, 32), dim3(32, 8), 0, stream>>>(Wo, WOT);
  gemm_proj<<<dim3(8, 16, 3), 512, 0, stream>>>(X1, X2, X3, W1, W2, W3, bq, bk, bv, PROJ);
  qnorm_kernel<<<256, 256, 0, stream>>>(PROJ, QN);
  topk_kernel<<<32, 256, 0, stream>>>(QN, TOPK, SELI, HMASK, qvl);
  scores_kernel<<<dim3(16, 32), 256, 0, stream>>>(PROJ, TOPK, maskp, SC, qvl, kvl);
  softmax_kernel<<<dim3(64, 32), 256, 0, stream>>>(SC, qvl, kvl);
  pv_mfma<<<dim3(16, 32), 256, 0, stream>>>(SC, VT, PART, kvl);
  pv_reduce<<<dim3(64, 32), 64, 0, stream>>>(PART, CTX, qvl, kvl);
  outproj_kernel<<<4096, 256, 0, stream>>>(CTX, WOT, bo, HMASK, SELI, out);
}

// Round 6
// 278.739 us; speedup vs baseline: 2.5511x; 1.0076x over previous
//
#include <hip/hip_runtime.h>

typedef unsigned short u16;
typedef __bf16 bf16x8 __attribute__((ext_vector_type(8)));
typedef float f32x4 __attribute__((ext_vector_type(4)));

// ---------- numeric helpers (RNE f32<->bf16, matching XLA/ml_dtypes) ----------
__device__ __forceinline__ u16 f2bf(float f){
  unsigned int x = __float_as_uint(f);
  unsigned int r = (x + 0x7FFFu + ((x >> 16) & 1u)) >> 16;
  return (u16)r;
}
__device__ __forceinline__ float bf2f(u16 u){
  return __uint_as_float(((unsigned int)u) << 16);
}
__device__ __forceinline__ int compute_u(int qvlv){
  int mm = qvlv > 2 ? qvlv : 2;
  int u = (int)(5.0 * log((double)mm));   // FACTOR=5.0, python int() truncation
  if (u < 1) u = 1;
  if (u > 64) u = 64;
  return u;
}
__device__ __forceinline__ void gload_lds16(const void* g, void* l){
  __builtin_amdgcn_global_load_lds(
      (const __attribute__((address_space(1))) void*)g,
      (__attribute__((address_space(3))) void*)l, 16, 0, 0);
}

// ---------- K1: split f32 -> 3 bf16 levels (X for q/k/v, W for Wq/Wk/Wv) ----------
__global__ void expand_kernel(const float* __restrict__ xq, const float* __restrict__ xk,
                              const float* __restrict__ xv,
                              const float* __restrict__ wq, const float* __restrict__ wk,
                              const float* __restrict__ wv,
                              u16* __restrict__ X1, u16* __restrict__ X2, u16* __restrict__ X3,
                              u16* __restrict__ W1, u16* __restrict__ W2, u16* __restrict__ W3)
{
  size_t g = (size_t)blockIdx.x * 256 + threadIdx.x;  // one group = 4 floats
  const float* src; u16 *d1, *d2, *d3;
  if (g < 3145728ull) {                 // X part: 3 * 4194304 / 4
    int p = (int)(g >> 20);
    size_t e = (g & 1048575ull) * 4;
    src = (p == 0 ? xq : (p == 1 ? xk : xv)) + e;
    size_t o = (size_t)p * 4194304ull + e;
    d1 = X1 + o; d2 = X2 + o; d3 = (p == 0) ? (X3 + e) : (u16*)0;
  } else {                              // W part: 3 * 1048576 / 4
    size_t wg = g - 3145728ull;
    int p = (int)(wg >> 18);
    size_t e = (wg & 262143ull) * 4;
    src = (p == 0 ? wq : (p == 1 ? wk : wv)) + e;
    size_t o = (size_t)p * 1048576ull + e;
    d1 = W1 + o; d2 = W2 + o; d3 = (p == 0) ? (W3 + e) : (u16*)0;
  }
  float4 x = *reinterpret_cast<const float4*>(src);
  float xs[4] = {x.x, x.y, x.z, x.w};
  u16 h1[4], h2[4], h3[4];
#pragma unroll
  for (int i = 0; i < 4; ++i){
    float v = xs[i];
    u16 a = f2bf(v);  float r1 = v  - bf2f(a);
    u16 b = f2bf(r1); float r2 = r1 - bf2f(b);
    u16 c = f2bf(r2);
    h1[i] = a; h2[i] = b; h3[i] = c;
  }
  *reinterpret_cast<ushort4*>(d1) = make_ushort4(h1[0], h1[1], h1[2], h1[3]);
  *reinterpret_cast<ushort4*>(d2) = make_ushort4(h2[0], h2[1], h2[2], h2[3]);
  if (d3) *reinterpret_cast<ushort4*>(d3) = make_ushort4(h3[0], h3[1], h3[2], h3[3]);
}

// ---------- K2: WoT[j][d] = Wo[d][j] ----------
__global__ void wot_kernel(const float* __restrict__ Wo, float* __restrict__ WoT){
  __shared__ float tile[32][33];
  int tx = threadIdx.x, ty = threadIdx.y;   // 32 x 8
  int bx = blockIdx.x * 32, by = blockIdx.y * 32;
#pragma unroll
  for (int r = 0; r < 4; ++r)
    tile[ty + r*8][tx] = Wo[(size_t)(by + ty + r*8) * 1024 + bx + tx];
  __syncthreads();
#pragma unroll
  for (int r = 0; r < 4; ++r)
    WoT[(size_t)(bx + ty + r*8) * 1024 + by + tx] = tile[tx][ty + r*8];
}

// ---------- K3: split-precision bf16 MFMA GEMM  C = X @ W^T + bias ----------
// 8 waves, BM=256 BN=128 BK=32, dbuf term-shared tile sets, counted-vmcnt
// schedule (T3+T4): STAGE(NXT) -> vmcnt(9|6) -> s_barrier -> ds_read+MFMA ->
// s_barrier. NXT's loads stay in flight across the whole compute phase.
// z=0: Q terms {00,01,10,11,02,20}; z>=1: {00,01,10}.
// z=2 epilogue writes VT split-bf16 transposed [b,h][128][2048].
__global__ __launch_bounds__(512, 1) void gemm_proj(
    const u16* __restrict__ X1, const u16* __restrict__ X2, const u16* __restrict__ X3,
    const u16* __restrict__ W1, const u16* __restrict__ W2, const u16* __restrict__ W3,
    const float* __restrict__ bq, const float* __restrict__ bk, const float* __restrict__ bv,
    float* __restrict__ PROJ)
{
  int z = blockIdx.z;
  // XCD-chunked bijective swizzle: 128 blocks/z, 8 XCDs, 16 per XCD
  int orig = blockIdx.x + blockIdx.y * 8;          // 0..127
  int wgid = (orig & 7) * 16 + (orig >> 3);
  int bx = wgid & 7, by = wgid >> 3;               // same-XCD blocks share by-panels

  const u16* Xa0 = X1 + (size_t)z * 4194304;
  const u16* Xa1 = X2 + (size_t)z * 4194304;
  const u16* Xa2 = X3;                       // only used when z==0
  const u16* Wb0 = W1 + (size_t)z * 1048576;
  const u16* Wb1 = W2 + (size_t)z * 1048576;
  const u16* Wb2 = W3;
  const float* bias = (z == 0) ? bq : (z == 1 ? bk : bv);
  float* C = PROJ + (size_t)z * 4194304;

  // dbuf tile sets: per set A0[256][32],A1,A2 (8192 u16 each) + B0[128][32],B1,B2 (4096)
  __shared__ __align__(16) u16 T[2 * 36864];       // 144 KB
  u16* SET0 = T;
  u16* SET1 = T + 36864;

  int t = threadIdx.x;
  int wave = t >> 6, lane = t & 63;
  int wm = wave >> 1, wn = wave & 1;               // 4 x 2 wave grid
  int lr = lane & 15, lk = lane >> 4;
  int rowA = by * 256, rowB = bx * 128;
  f32x4 acc[4][4] = {};
  bf16x8 afA[4], afB[4], afC[4], bgA[4], bgB[4], bgC[4];

#define STAGEA(dstbase, G)                                                    \
  {                                                                           \
    _Pragma("unroll")                                                         \
    for (int i = 0; i < 2; ++i){                                              \
      int p = i * 512 + t;                                                    \
      int r = p >> 2;                                                         \
      int c = (p & 3) ^ ((r >> 1) & 3);                                       \
      gload_lds16(G + (size_t)(rowA + r) * 1024 + pk + c * 8,                 \
                  (dstbase) + p * 8);                                         \
    }                                                                         \
  }
#define STAGEB(dstbase, G)                                                    \
  {                                                                           \
    int p = t;                                                                \
    int r = p >> 2;                                                           \
    int c = (p & 3) ^ ((r >> 1) & 3);                                         \
    gload_lds16(G + (size_t)(rowB + r) * 1024 + pk + c * 8,                   \
                (dstbase) + p * 8);                                           \
  }
#define LOADA(dst, tile)                                                      \
  {                                                                           \
    _Pragma("unroll")                                                         \
    for (int m = 0; m < 4; ++m){                                              \
      int r = wm * 64 + m * 16 + lr;                                          \
      dst[m] = *reinterpret_cast<const bf16x8*>(                              \
          &(tile)[r * 32 + ((lk ^ ((r >> 1) & 3)) << 3)]);                    \
    }                                                                         \
  }
#define LOADB(dst, tile)                                                      \
  {                                                                           \
    _Pragma("unroll")                                                         \
    for (int n = 0; n < 4; ++n){                                              \
      int r = wn * 64 + n * 16 + lr;                                          \
      dst[n] = *reinterpret_cast<const bf16x8*>(                              \
          &(tile)[r * 32 + ((lk ^ ((r >> 1) & 3)) << 3)]);                    \
    }                                                                         \
  }
#define GRPX(A_, B_)                                                          \
  {                                                                           \
    __builtin_amdgcn_s_setprio(1);                                            \
    _Pragma("unroll")                                                         \
    for (int m = 0; m < 4; ++m)                                               \
      _Pragma("unroll")                                                       \
      for (int n = 0; n < 4; ++n)                                             \
        acc[m][n] = __builtin_amdgcn_mfma_f32_16x16x32_bf16(A_[m], B_[n],     \
                                                            acc[m][n], 0,0,0);\
    __builtin_amdgcn_s_setprio(0);                                            \
  }

  if (z == 0){
    { int pk = 0;                       // prologue: stage chunk 0 (9 loads)
      STAGEA(SET0, Xa0); STAGEA(SET0 + 8192, Xa1); STAGEA(SET0 + 16384, Xa2);
      STAGEB(SET0 + 24576, Wb0); STAGEB(SET0 + 28672, Wb1); STAGEB(SET0 + 32768, Wb2);
    }
    for (int kt = 0; kt < 32; ++kt){
      u16* CUR = (kt & 1) ? SET1 : SET0;
      u16* NXT = (kt & 1) ? SET0 : SET1;
      if (kt < 31){
        int pk = (kt + 1) * 32;         // issue next-chunk loads (stay in flight)
        STAGEA(NXT, Xa0); STAGEA(NXT + 8192, Xa1); STAGEA(NXT + 16384, Xa2);
        STAGEB(NXT + 24576, Wb0); STAGEB(NXT + 28672, Wb1); STAGEB(NXT + 32768, Wb2);
      }
      __builtin_amdgcn_sched_barrier(0);
      if (kt < 31) asm volatile("s_waitcnt vmcnt(9)" ::: "memory");
      else         asm volatile("s_waitcnt vmcnt(0)" ::: "memory");
      __builtin_amdgcn_s_barrier();     // all waves' CUR tiles landed
      __builtin_amdgcn_sched_barrier(0);
      u16* A0t = CUR;          u16* A1t = CUR + 8192;  u16* A2t = CUR + 16384;
      u16* B0t = CUR + 24576;  u16* B1t = CUR + 28672; u16* B2t = CUR + 32768;
      LOADA(afA, A0t); LOADB(bgA, B0t); GRPX(afA, bgA);   // 00
      LOADB(bgB, B1t);                  GRPX(afA, bgB);   // 01
      LOADA(afB, A1t);                  GRPX(afB, bgA);   // 10
                                        GRPX(afB, bgB);   // 11
      LOADB(bgC, B2t);                  GRPX(afA, bgC);   // 02
      LOADA(afC, A2t);                  GRPX(afC, bgA);   // 20
      __builtin_amdgcn_sched_barrier(0);
      __builtin_amdgcn_s_barrier();     // reads done before NXT-stage overwrites
    }
  } else {
    { int pk = 0;                       // prologue: stage chunk 0 (6 loads)
      STAGEA(SET0, Xa0); STAGEA(SET0 + 8192, Xa1);
      STAGEB(SET0 + 24576, Wb0); STAGEB(SET0 + 28672, Wb1);
    }
    for (int kt = 0; kt < 32; ++kt){
      u16* CUR = (kt & 1) ? SET1 : SET0;
      u16* NXT = (kt & 1) ? SET0 : SET1;
      if (kt < 31){
        int pk = (kt + 1) * 32;
        STAGEA(NXT, Xa0); STAGEA(NXT + 8192, Xa1);
        STAGEB(NXT + 24576, Wb0); STAGEB(NXT + 28672, Wb1);
      }
      __builtin_amdgcn_sched_barrier(0);
      if (kt < 31) asm volatile("s_waitcnt vmcnt(6)" ::: "memory");
      else         asm volatile("s_waitcnt vmcnt(0)" ::: "memory");
      __builtin_amdgcn_s_barrier();
      __builtin_amdgcn_sched_barrier(0);
      u16* A0t = CUR;          u16* A1t = CUR + 8192;
      u16* B0t = CUR + 24576;  u16* B1t = CUR + 28672;
      LOADA(afA, A0t); LOADB(bgA, B0t); GRPX(afA, bgA);   // 00
      LOADB(bgB, B1t);                  GRPX(afA, bgB);   // 01
      LOADA(afB, A1t);                  GRPX(afB, bgA);   // 10
      __builtin_amdgcn_sched_barrier(0);
      __builtin_amdgcn_s_barrier();
    }
  }
#undef STAGEA
#undef STAGEB
#undef LOADA
#undef LOADB
#undef GRPX

  if (z < 2){
#pragma unroll
    for (int m = 0; m < 4; ++m){
      int row0 = by * 256 + wm * 64 + m * 16 + (lane >> 4) * 4;
#pragma unroll
      for (int n = 0; n < 4; ++n){
        int col = bx * 128 + wn * 64 + n * 16 + (lane & 15);
        float bb = bias[col];
#pragma unroll
        for (int j = 0; j < 4; ++j)
          C[(size_t)(row0 + j) * 1024 + col] = acc[m][n][j] + bb;
      }
    }
  } else {
    u16* VT = (u16*)C;   // [32][128][2048] u16 (aliases PROJ z==2 slice)
#pragma unroll
    for (int m = 0; m < 4; ++m){
      int r0 = by * 256 + wm * 64 + m * 16 + (lane >> 4) * 4;
      int b = r0 >> 11, kb = r0 & 2047;
#pragma unroll
      for (int n = 0; n < 4; ++n){
        int c = bx * 128 + wn * 64 + n * 16 + (lane & 15);
        float bb = bias[c];
        int h = c >> 6, d = c & 63;
        u16 hi[4], lo[4];
#pragma unroll
        for (int j = 0; j < 4; ++j){
          float v = acc[m][n][j] + bb;
          hi[j] = f2bf(v);
          lo[j] = f2bf(v - bf2f(hi[j]));
        }
        size_t base = ((size_t)(b * 16 + h) * 128) * 2048 + (size_t)kb;
        *reinterpret_cast<ushort4*>(&VT[base + (size_t)d * 2048]) =
            make_ushort4(hi[0], hi[1], hi[2], hi[3]);
        *reinterpret_cast<ushort4*>(&VT[base + (size_t)(64 + d) * 2048]) =
            make_ushort4(lo[0], lo[1], lo[2], lo[3]);
      }
    }
  }
}

// ---------- K4: q_norm[b,h,l] = sum_d Q[b,l,h*64+d]^2 ----------
__global__ void qnorm_kernel(const float* __restrict__ PROJ, float* __restrict__ qn){
  int g = blockIdx.x * 256 + threadIdx.x;   // 65536
  int b = g >> 15, rem = g & 32767, h = rem >> 11, l = rem & 2047;
  const float* q = PROJ + (size_t)(b * 2048 + l) * 1024 + h * 64;
  float s = 0.f;
#pragma unroll 8
  for (int d = 0; d < 64; ++d){ float x = q[d]; s += x * x; }
  qn[(size_t)(b * 16 + h) * 2048 + l] = s;
}

// ---------- K5: top-u argmax per (b,h); regs + shfl butterfly; tie -> lower idx ----------
__global__ __launch_bounds__(512) void topk_kernel(
    const float* __restrict__ qn, int* __restrict__ topk,
    unsigned char* __restrict__ seli, unsigned int* __restrict__ hmask,
    const int* __restrict__ qvlp){
  int bh = blockIdx.x; int b = bh >> 4, h = bh & 15;
  int u = compute_u(qvlp[0]);
  int t = threadIdx.x;                       // 512 threads, 4 values each
  float4 v4 = *reinterpret_cast<const float4*>(qn + (size_t)bh * 2048 + t * 4);
  float v[4] = {v4.x, v4.y, v4.z, v4.w};
  __shared__ float swv[8];
  __shared__ int swi[8];
  __shared__ int sidx;
  int lane = t & 63, w = t >> 6;
  for (int it = 0; it < u; ++it){
    float bv = v[0]; int bi = t * 4;
#pragma unroll
    for (int j = 1; j < 4; ++j){
      if (v[j] > bv){ bv = v[j]; bi = t * 4 + j; }      // strict >: keeps lower idx
    }
#pragma unroll
    for (int off = 1; off < 64; off <<= 1){
      float ov = __shfl_xor(bv, off);
      int   oi = __shfl_xor(bi, off);
      if (ov > bv || (ov == bv && oi < bi)){ bv = ov; bi = oi; }
    }
    if (lane == 0){ swv[w] = bv; swi[w] = bi; }
    __syncthreads();
    if (t == 0){
      float fv = swv[0]; int fi = swi[0];
#pragma unroll
      for (int k = 1; k < 8; ++k){
        if (swv[k] > fv || (swv[k] == fv && swi[k] < fi)){ fv = swv[k]; fi = swi[k]; }
      }
      sidx = fi;
      topk[bh * 64 + it] = fi;
      seli[(size_t)bh * 2048 + fi] = (unsigned char)it;
      atomicOr(&hmask[b * 2048 + fi], 1u << h);
    }
    __syncthreads();
    int idx = sidx;
    if ((idx >> 2) == t) v[idx & 3] = -3.4e38f;
  }
}

// ---------- K6: scores for selected rows; bf16 round + bf16 mask add ----------
__global__ void scores_kernel(const float* __restrict__ PROJ, const int* __restrict__ topk,
                              const float* __restrict__ maskp, u16* __restrict__ sc,
                              const int* __restrict__ qvlp, const int* __restrict__ kvlp){
  int bh = blockIdx.y; int b = bh >> 4, h = bh & 15;
  int kvlv = kvlp[0]; if (kvlv > 2048) kvlv = 2048; if (kvlv < 0) kvlv = 0;
  int u = compute_u(qvlp[0]);
  int k0 = blockIdx.x * 128;
  if (k0 >= kvlv) return;
  int kcnt = kvlv - k0; if (kcnt > 128) kcnt = 128;
  int t = threadIdx.x;
  __shared__ int idx_l[64];
  __shared__ float qld[64 * 64];
  __shared__ float kld[128 * 65];
  const float* Q = PROJ;
  const float* K = PROJ + 4194304;
  if (t < u) idx_l[t] = topk[bh * 64 + t];
  __syncthreads();
  for (int e = t; e < u * 64; e += 256){
    int i = e >> 6, d = e & 63;
    qld[e] = Q[(size_t)(b * 2048 + idx_l[i]) * 1024 + h * 64 + d];
  }
  for (int e = t; e < 128 * 64; e += 256){
    int kk = e >> 6, d = e & 63;
    float vv = (kk < kcnt) ? K[(size_t)(b * 2048 + k0 + kk) * 1024 + h * 64 + d] : 0.f;
    kld[kk * 65 + d] = vv;
  }
  __syncthreads();
  for (int e = t; e < u * 128; e += 256){
    int i = e >> 7, kk = e & 127;
    if (kk >= kcnt) continue;
    const float* qr = &qld[i * 64];
    const float* kr = &kld[kk * 65];
    float s = 0.f;
#pragma unroll 8
    for (int d = 0; d < 64; ++d) s += qr[d] * kr[d];
    s *= 0.125f;                          // / sqrt(64)
    int l = idx_l[i]; int k = k0 + kk;
    u16 xb = f2bf(s);                     // scores.astype(bf16)
    u16 mb = f2bf(maskp[(size_t)l * 2048 + k]);   // attn_mask.astype(bf16) (kpm=0 here)
    u16 xm = f2bf(bf2f(xb) + bf2f(mb));   // bf16 add
    sc[(size_t)(bh * 64 + i) * 2048 + k] = xm;
  }
}

// ---------- K7: exact bf16 softmax emulation; p written in place ----------
__global__ void softmax_kernel(u16* __restrict__ sc, const int* __restrict__ qvlp,
                               const int* __restrict__ kvlp){
  int bh = blockIdx.y, i = blockIdx.x;
  int u = compute_u(qvlp[0]);
  if (i >= u) return;
  int kvlv = kvlp[0]; if (kvlv > 2048) kvlv = 2048; if (kvlv < 0) kvlv = 0;
  u16* row = sc + (size_t)(bh * 64 + i) * 2048;
  int t = threadIdx.x;
  float x[8];
  float lm = -3.4e38f;
#pragma unroll
  for (int j = 0; j < 8; ++j){
    int k = t + j * 256;
    x[j] = (k < kvlv) ? bf2f(row[k]) : -3.4e38f;
    lm = fmaxf(lm, x[j]);
  }
  __shared__ float red[256];
  red[t] = lm; __syncthreads();
  for (int s = 128; s > 0; s >>= 1){ if (t < s) red[t] = fmaxf(red[t], red[t+s]); __syncthreads(); }
  float m = red[0];
  __syncthreads();
  float e[8]; float ls = 0.f;
#pragma unroll
  for (int j = 0; j < 8; ++j){
    int k = t + j * 256;
    if (k < kvlv){
      u16 ub = f2bf(x[j] - m);            // bf16 subtract
      u16 eb = f2bf(expf(bf2f(ub)));      // bf16 exp
      e[j] = bf2f(eb);
      ls += e[j];
    } else e[j] = 0.f;
  }
  red[t] = ls; __syncthreads();
  for (int s = 128; s > 0; s >>= 1){ if (t < s) red[t] += red[t+s]; __syncthreads(); }
  float S = red[0];                       // f32 accumulation (jnp.sum upcast)
  float Sb = bf2f(f2bf(S));               // downcast back to bf16
#pragma unroll
  for (int j = 0; j < 8; ++j){
    int k = t + j * 256;
    if (k < 2048) row[k] = (k < kvlv) ? f2bf(e[j] / Sb) : (u16)0;   // bf16 divide
  }
}

// ---------- K8a: PV via MFMA, no LDS. part[kc][bh][64 rows][64 d] ----------
__global__ void pv_mfma(const u16* __restrict__ probs, const u16* __restrict__ VT,
                        float* __restrict__ part, const int* __restrict__ kvlp)
{
  int bh = blockIdx.y; int b = bh >> 4, h = bh & 15;
  int kvlv = kvlp[0]; if (kvlv > 2048) kvlv = 2048; if (kvlv < 0) kvlv = 0;
  int kc = blockIdx.x;
  int k0 = kc * 128;
  if (k0 >= kvlv) return;
  int t = threadIdx.x, w = t >> 6, lane = t & 63;
  int lr = lane & 15, lk = lane >> 4;
  const u16* Pb = probs + (size_t)bh * 64 * 2048;
  const u16* Vb = VT + (size_t)(b * 16 + h) * 128 * 2048;
  f32x4 acc[4] = {};
#pragma unroll
  for (int ks = 0; ks < 4; ++ks){
    int kk = k0 + ks * 32 + lk * 8;
    bf16x8 A0 = *reinterpret_cast<const bf16x8*>(Pb + (size_t)(lr     ) * 2048 + kk);
    bf16x8 A1 = *reinterpret_cast<const bf16x8*>(Pb + (size_t)(lr + 16) * 2048 + kk);
    bf16x8 A2 = *reinterpret_cast<const bf16x8*>(Pb + (size_t)(lr + 32) * 2048 + kk);
    bf16x8 A3 = *reinterpret_cast<const bf16x8*>(Pb + (size_t)(lr + 48) * 2048 + kk);
    bf16x8 Bh = *reinterpret_cast<const bf16x8*>(Vb + (size_t)(w * 16 + lr     ) * 2048 + kk);
    bf16x8 Bl = *reinterpret_cast<const bf16x8*>(Vb + (size_t)(w * 16 + lr + 64) * 2048 + kk);
    acc[0] = __builtin_amdgcn_mfma_f32_16x16x32_bf16(A0, Bh, acc[0], 0, 0, 0);
    acc[1] = __builtin_amdgcn_mfma_f32_16x16x32_bf16(A1, Bh, acc[1], 0, 0, 0);
    acc[2] = __builtin_amdgcn_mfma_f32_16x16x32_bf16(A2, Bh, acc[2], 0, 0, 0);
    acc[3] = __builtin_amdgcn_mfma_f32_16x16x32_bf16(A3, Bh, acc[3], 0, 0, 0);
    acc[0] = __builtin_amdgcn_mfma_f32_16x16x32_bf16(A0, Bl, acc[0], 0, 0, 0);
    acc[1] = __builtin_amdgcn_mfma_f32_16x16x32_bf16(A1, Bl, acc[1], 0, 0, 0);
    acc[2] = __builtin_amdgcn_mfma_f32_16x16x32_bf16(A2, Bl, acc[2], 0, 0, 0);
    acc[3] = __builtin_amdgcn_mfma_f32_16x16x32_bf16(A3, Bl, acc[3], 0, 0, 0);
  }
  float* pc = part + (size_t)(kc * 32 + bh) * 64 * 64;
#pragma unroll
  for (int m = 0; m < 4; ++m){
    int row = m * 16 + lk * 4;
#pragma unroll
    for (int j = 0; j < 4; ++j)
      pc[(size_t)(row + j) * 64 + w * 16 + lr] = acc[m][j];
  }
}

// ---------- K8b: deterministic reduction of PV partials ----------
__global__ void pv_reduce(const float* __restrict__ part, float* __restrict__ ctx,
                          const int* __restrict__ qvlp, const int* __restrict__ kvlp){
  int bh = blockIdx.y, r = blockIdx.x;
  int u = compute_u(qvlp[0]);
  if (r >= u) return;
  int kvlv = kvlp[0]; if (kvlv > 2048) kvlv = 2048; if (kvlv < 0) kvlv = 0;
  int kcmax = (kvlv + 127) / 128;
  int d = threadIdx.x;   // 64
  float s = 0.f;
  for (int kc = 0; kc < kcmax; ++kc)
    s += part[(size_t)((kc * 32 + bh) * 64 + r) * 64 + d];
  ctx[(size_t)(bh * 64 + r) * 64 + d] = s;
}

// ---------- K9: sparse output projection; unselected rows = bo ----------
__global__ void outproj_kernel(const float* __restrict__ ctx, const float* __restrict__ WoT,
                               const float* __restrict__ bo, const unsigned int* __restrict__ hmask,
                               const unsigned char* __restrict__ seli, float* __restrict__ out){
  int row = blockIdx.x;                 // b*2048 + l
  int b = row >> 11, l = row & 2047;
  int t = threadIdx.x;
  float acc[4];
#pragma unroll
  for (int r = 0; r < 4; ++r) acc[r] = bo[t + r * 256];
  unsigned int m = hmask[row];
  __shared__ float clds[64];
  while (m){
    int h = __ffs(m) - 1; m &= (m - 1);
    int i = (int)seli[(size_t)(b * 16 + h) * 2048 + l];
    __syncthreads();
    if (t < 64) clds[t] = ctx[(size_t)((b * 16 + h) * 64 + i) * 64 + t];
    __syncthreads();
    for (int j = 0; j < 64; ++j){
      float c = clds[j];
      const float* wrow = &WoT[(size_t)(h * 64 + j) * 1024];
#pragma unroll
      for (int r = 0; r < 4; ++r) acc[r] += c * wrow[t + r * 256];
    }
  }
  float* orow = out + (size_t)row * 1024;
#pragma unroll
  for (int r = 0; r < 4; ++r) orow[t + r * 256] = acc[r];
}

__global__ void fail_fill(float* o, int n){
  int i = blockIdx.x * 256 + threadIdx.x;
  if (i < n) o[i] = 12345.0f;
}

// ---------------------------------------------------------------------------
extern "C" void kernel_launch(void* const* d_in, const int* in_sizes, int n_in,
                              void* d_out, int out_size, void* d_ws, size_t ws_size,
                              hipStream_t stream)
{
  const float* query = (const float*)d_in[0];
  const float* key   = (const float*)d_in[1];
  const float* value = (const float*)d_in[2];
  const float* maskp = (const float*)d_in[3];
  const float* Wq = (const float*)d_in[4];
  const float* bq = (const float*)d_in[5];
  const float* Wk = (const float*)d_in[6];
  const float* bk = (const float*)d_in[7];
  const float* Wv = (const float*)d_in[8];
  const float* bv = (const float*)d_in[9];
  const float* Wo = (const float*)d_in[10];
  const float* bo = (const float*)d_in[11];
  const int* qvl = (const int*)d_in[12];
  const int* kvl = (const int*)d_in[13];
  float* out = (float*)d_out;

  char* ws = (char*)d_ws;
  size_t off = 0;
  auto alloc = [&](size_t bytes) -> void* {
    void* p = ws + off;
    off = (off + bytes + 255) & ~(size_t)255;
    return p;
  };
  u16* X1 = (u16*)alloc(3ull * 4194304 * 2);
  u16* X2 = (u16*)alloc(3ull * 4194304 * 2);
  u16* X3 = (u16*)alloc(1ull * 4194304 * 2);
  u16* W1 = (u16*)alloc(3ull * 1048576 * 2);
  u16* W2 = (u16*)alloc(3ull * 1048576 * 2);
  u16* W3 = (u16*)alloc(1ull * 1048576 * 2);
  float* PROJ = (float*)alloc(3ull * 4194304 * 4);
  float* WOT  = (float*)alloc(4194304ull);
  float* QN   = (float*)alloc(2ull * 16 * 2048 * 4);
  int*   TOPK = (int*)alloc(2ull * 16 * 64 * 4);
  unsigned char* SELI = (unsigned char*)alloc(2ull * 16 * 2048);
  unsigned int* HMASK = (unsigned int*)alloc(2ull * 2048 * 4);
  u16*   SC   = (u16*)alloc(2048ull * 2048 * 2);
  float* CTX  = (float*)alloc(2048ull * 64 * 4);

  // VT (split-bf16 transposed V) aliases the PROJ z==2 slice (exactly 16.78 MB)
  u16* VT = (u16*)(PROJ + 2ull * 4194304);
  // PV partials alias X1 (24 MB, dead after gemm_proj): 16*32*64*64*4 = 8.4 MB
  float* PART = (float*)X1;

  if (ws_size < off){
    fail_fill<<<(out_size + 255) / 256, 256, 0, stream>>>(out, out_size);
    return;
  }

  hipMemsetAsync(SELI, 0xFF, 2ull * 16 * 2048, stream);
  hipMemsetAsync(HMASK, 0, 2ull * 2048 * 4, stream);

  expand_kernel<<<15360, 256, 0, stream>>>(query, key, value, Wq, Wk, Wv,
                                           X1, X2, X3, W1, W2, W3);
  wot_kernel<<<dim3(32, 32), dim3(32, 8), 0, stream>>>(Wo, WOT);
  gemm_proj<<<dim3(8, 16, 3), 512, 0, stream>>>(X1, X2, X3, W1, W2, W3, bq, bk, bv, PROJ);
  qnorm_kernel<<<256, 256, 0, stream>>>(PROJ, QN);
  topk_kernel<<<32, 512, 0, stream>>>(QN, TOPK, SELI, HMASK, qvl);
  scores_kernel<<<dim3(16, 32), 256, 0, stream>>>(PROJ, TOPK, maskp, SC, qvl, kvl);
  softmax_kernel<<<dim3(64, 32), 256, 0, stream>>>(SC, qvl, kvl);
  pv_mfma<<<dim3(16, 32), 256, 0, stream>>>(SC, VT, PART, kvl);
  pv_reduce<<<dim3(64, 32), 64, 0, stream>>>(PART, CTX, qvl, kvl);
  outproj_kernel<<<4096, 256, 0, stream>>>(CTX, WOT, bo, HMASK, SELI, out);
}

// Round 7
// 266.529 us; speedup vs baseline: 2.6680x; 1.0458x over previous
//
#include <hip/hip_runtime.h>

typedef unsigned short u16;
typedef __bf16 bf16x8 __attribute__((ext_vector_type(8)));
typedef float f32x4 __attribute__((ext_vector_type(4)));

// ---------- numeric helpers (RNE f32<->bf16, matching XLA/ml_dtypes) ----------
__device__ __forceinline__ u16 f2bf(float f){
  unsigned int x = __float_as_uint(f);
  unsigned int r = (x + 0x7FFFu + ((x >> 16) & 1u)) >> 16;
  return (u16)r;
}
__device__ __forceinline__ float bf2f(u16 u){
  return __uint_as_float(((unsigned int)u) << 16);
}
__device__ __forceinline__ int compute_u(int qvlv){
  int mm = qvlv > 2 ? qvlv : 2;
  int u = (int)(5.0 * log((double)mm));   // FACTOR=5.0, python int() truncation
  if (u < 1) u = 1;
  if (u > 64) u = 64;
  return u;
}
__device__ __forceinline__ void gload_lds16(const void* g, void* l){
  __builtin_amdgcn_global_load_lds(
      (const __attribute__((address_space(1))) void*)g,
      (__attribute__((address_space(3))) void*)l, 16, 0, 0);
}

// ---------- K1: split f32 -> 3 bf16 levels (X for q/k/v, W for Wq/Wk/Wv) ----------
__global__ void expand_kernel(const float* __restrict__ xq, const float* __restrict__ xk,
                              const float* __restrict__ xv,
                              const float* __restrict__ wq, const float* __restrict__ wk,
                              const float* __restrict__ wv,
                              u16* __restrict__ X1, u16* __restrict__ X2, u16* __restrict__ X3,
                              u16* __restrict__ W1, u16* __restrict__ W2, u16* __restrict__ W3)
{
  size_t g = (size_t)blockIdx.x * 256 + threadIdx.x;  // one group = 4 floats
  const float* src; u16 *d1, *d2, *d3;
  if (g < 3145728ull) {                 // X part: 3 * 4194304 / 4
    int p = (int)(g >> 20);
    size_t e = (g & 1048575ull) * 4;
    src = (p == 0 ? xq : (p == 1 ? xk : xv)) + e;
    size_t o = (size_t)p * 4194304ull + e;
    d1 = X1 + o; d2 = X2 + o; d3 = (p == 0) ? (X3 + e) : (u16*)0;
  } else {                              // W part: 3 * 1048576 / 4
    size_t wg = g - 3145728ull;
    int p = (int)(wg >> 18);
    size_t e = (wg & 262143ull) * 4;
    src = (p == 0 ? wq : (p == 1 ? wk : wv)) + e;
    size_t o = (size_t)p * 1048576ull + e;
    d1 = W1 + o; d2 = W2 + o; d3 = (p == 0) ? (W3 + e) : (u16*)0;
  }
  float4 x = *reinterpret_cast<const float4*>(src);
  float xs[4] = {x.x, x.y, x.z, x.w};
  u16 h1[4], h2[4], h3[4];
#pragma unroll
  for (int i = 0; i < 4; ++i){
    float v = xs[i];
    u16 a = f2bf(v);  float r1 = v  - bf2f(a);
    u16 b = f2bf(r1); float r2 = r1 - bf2f(b);
    u16 c = f2bf(r2);
    h1[i] = a; h2[i] = b; h3[i] = c;
  }
  *reinterpret_cast<ushort4*>(d1) = make_ushort4(h1[0], h1[1], h1[2], h1[3]);
  *reinterpret_cast<ushort4*>(d2) = make_ushort4(h2[0], h2[1], h2[2], h2[3]);
  if (d3) *reinterpret_cast<ushort4*>(d3) = make_ushort4(h3[0], h3[1], h3[2], h3[3]);
}

// ---------- K2: WoT[j][d] = Wo[d][j] ----------
__global__ void wot_kernel(const float* __restrict__ Wo, float* __restrict__ WoT){
  __shared__ float tile[32][33];
  int tx = threadIdx.x, ty = threadIdx.y;   // 32 x 8
  int bx = blockIdx.x * 32, by = blockIdx.y * 32;
#pragma unroll
  for (int r = 0; r < 4; ++r)
    tile[ty + r*8][tx] = Wo[(size_t)(by + ty + r*8) * 1024 + bx + tx];
  __syncthreads();
#pragma unroll
  for (int r = 0; r < 4; ++r)
    WoT[(size_t)(bx + ty + r*8) * 1024 + by + tx] = tile[tx][ty + r*8];
}

// ---------- K3: split-precision bf16 MFMA GEMM  C = X @ W^T + bias ----------
// R5 schedule (proven 106us): 8 waves, BM=256 BN=128 BK=32, dbuf term-shared
// tile sets, stage-ahead + single __syncthreads per chunk, setprio on MFMA.
// z=0: Q terms {01,11,10,00,02,20} -> f32 PROJ
// z=1: K terms {00,01,10} -> KS split-bf16 [b,h][key][128] (hi|lo)
// z=2: V terms {00,01,10} -> VT split-bf16 transposed [b,h][128][2048]
__global__ __launch_bounds__(512, 1) void gemm_proj(
    const u16* __restrict__ X1, const u16* __restrict__ X2, const u16* __restrict__ X3,
    const u16* __restrict__ W1, const u16* __restrict__ W2, const u16* __restrict__ W3,
    const float* __restrict__ bq, const float* __restrict__ bk, const float* __restrict__ bv,
    float* __restrict__ PROJ)
{
  int z = blockIdx.z;
  // XCD-chunked bijective swizzle: 128 blocks/z, 8 XCDs, 16 per XCD
  int orig = blockIdx.x + blockIdx.y * 8;          // 0..127
  int wgid = (orig & 7) * 16 + (orig >> 3);
  int bx = wgid & 7, by = wgid >> 3;               // same-XCD blocks share by-panels

  const u16* Xa0 = X1 + (size_t)z * 4194304;
  const u16* Xa1 = X2 + (size_t)z * 4194304;
  const u16* Xa2 = X3;                       // only used when z==0
  const u16* Wb0 = W1 + (size_t)z * 1048576;
  const u16* Wb1 = W2 + (size_t)z * 1048576;
  const u16* Wb2 = W3;
  const float* bias = (z == 0) ? bq : (z == 1 ? bk : bv);
  float* C = PROJ + (size_t)z * 4194304;

  // dbuf tile sets: per set A0[256][32],A1,A2 (8192 u16 each) + B0[128][32],B1,B2 (4096)
  __shared__ __align__(16) u16 T[2 * 36864];       // 144 KB
  u16* SET0 = T;
  u16* SET1 = T + 36864;

  int t = threadIdx.x;
  int wave = t >> 6, lane = t & 63;
  int wm = wave >> 1, wn = wave & 1;               // 4 x 2 wave grid
  int lr = lane & 15, lk = lane >> 4;
  int rowA = by * 256, rowB = bx * 128;
  f32x4 acc[4][4] = {};
  bf16x8 afA[4], afB[4], bgA[4], bgB[4];

#define STAGEA(dstbase, G)                                                    \
  {                                                                           \
    _Pragma("unroll")                                                         \
    for (int i = 0; i < 2; ++i){                                              \
      int p = i * 512 + t;                                                    \
      int r = p >> 2;                                                         \
      int c = (p & 3) ^ ((r >> 1) & 3);                                       \
      gload_lds16(G + (size_t)(rowA + r) * 1024 + pk + c * 8,                 \
                  (dstbase) + p * 8);                                         \
    }                                                                         \
  }
#define STAGEB(dstbase, G)                                                    \
  {                                                                           \
    int p = t;                                                                \
    int r = p >> 2;                                                           \
    int c = (p & 3) ^ ((r >> 1) & 3);                                         \
    gload_lds16(G + (size_t)(rowB + r) * 1024 + pk + c * 8,                   \
                (dstbase) + p * 8);                                           \
  }
#define STAGE_SET(S)                                                          \
  {                                                                           \
    STAGEA((S), Xa0); STAGEA((S) + 8192, Xa1);                                \
    STAGEB((S) + 24576, Wb0); STAGEB((S) + 28672, Wb1);                       \
    if (z == 0){ STAGEA((S) + 16384, Xa2); STAGEB((S) + 32768, Wb2); }        \
  }
#define LOADA(dst, tile)                                                      \
  {                                                                           \
    _Pragma("unroll")                                                         \
    for (int m = 0; m < 4; ++m){                                              \
      int r = wm * 64 + m * 16 + lr;                                          \
      dst[m] = *reinterpret_cast<const bf16x8*>(                              \
          &(tile)[r * 32 + ((lk ^ ((r >> 1) & 3)) << 3)]);                    \
    }                                                                         \
  }
#define LOADB(dst, tile)                                                      \
  {                                                                           \
    _Pragma("unroll")                                                         \
    for (int n = 0; n < 4; ++n){                                              \
      int r = wn * 64 + n * 16 + lr;                                          \
      dst[n] = *reinterpret_cast<const bf16x8*>(                              \
          &(tile)[r * 32 + ((lk ^ ((r >> 1) & 3)) << 3)]);                    \
    }                                                                         \
  }
#define GRPX(A_, B_)                                                          \
  {                                                                           \
    __builtin_amdgcn_s_setprio(1);                                            \
    _Pragma("unroll")                                                         \
    for (int m = 0; m < 4; ++m)                                               \
      _Pragma("unroll")                                                       \
      for (int n = 0; n < 4; ++n)                                             \
        acc[m][n] = __builtin_amdgcn_mfma_f32_16x16x32_bf16(A_[m], B_[n],     \
                                                            acc[m][n], 0,0,0);\
    __builtin_amdgcn_s_setprio(0);                                            \
  }

  {                                    // prologue: stage chunk 0
    int pk = 0;
    STAGE_SET(SET0);
  }
  __syncthreads();

  for (int kt = 0; kt < 32; ++kt){
    u16* CUR = (kt & 1) ? SET1 : SET0;
    u16* NXT = (kt & 1) ? SET0 : SET1;
    if (kt < 31){
      int pk = (kt + 1) * 32;
      STAGE_SET(NXT);                  // issue next-chunk loads (hidden under MFMA)
    }
    __builtin_amdgcn_sched_barrier(0); // keep stage-issue ahead of compute
    u16* A0t = CUR;          u16* A1t = CUR + 8192;  u16* A2t = CUR + 16384;
    u16* B0t = CUR + 24576;  u16* B1t = CUR + 28672; u16* B2t = CUR + 32768;
    if (z == 0){
      LOADA(afA, A0t); LOADB(bgA, B1t);
      LOADA(afB, A1t); GRPX(afA, bgA);   // A0*B1
      LOADB(bgB, B0t); GRPX(afB, bgA);   // A1*B1
      LOADA(afA, A0t); GRPX(afB, bgB);   // A1*B0
      LOADB(bgA, B2t); GRPX(afA, bgB);   // A0*B0
      LOADA(afB, A2t); GRPX(afA, bgA);   // A0*B2
                       GRPX(afB, bgB);   // A2*B0
    } else {
      LOADA(afA, A0t); LOADB(bgA, B0t);
      LOADB(bgB, B1t); GRPX(afA, bgA);   // A0*B0
      LOADA(afB, A1t); GRPX(afA, bgB);   // A0*B1
                       GRPX(afB, bgA);   // A1*B0
    }
    __syncthreads();                   // drains vmcnt: next chunk staged & visible
  }
#undef STAGEA
#undef STAGEB
#undef STAGE_SET
#undef LOADA
#undef LOADB
#undef GRPX

  if (z == 0){
#pragma unroll
    for (int m = 0; m < 4; ++m){
      int row0 = by * 256 + wm * 64 + m * 16 + (lane >> 4) * 4;
#pragma unroll
      for (int n = 0; n < 4; ++n){
        int col = bx * 128 + wn * 64 + n * 16 + (lane & 15);
        float bb = bias[col];
#pragma unroll
        for (int j = 0; j < 4; ++j)
          C[(size_t)(row0 + j) * 1024 + col] = acc[m][n][j] + bb;
      }
    }
  } else if (z == 1){
    u16* KS = (u16*)C;   // [32][2048][128] u16 (hi|lo planes), aliases K f32 slice
#pragma unroll
    for (int m = 0; m < 4; ++m){
      int r0 = by * 256 + wm * 64 + m * 16 + (lane >> 4) * 4;
      int b = r0 >> 11, kb = r0 & 2047;
#pragma unroll
      for (int n = 0; n < 4; ++n){
        int c = bx * 128 + wn * 64 + n * 16 + (lane & 15);
        float bb = bias[c];
        int h = c >> 6, d = c & 63;
#pragma unroll
        for (int j = 0; j < 4; ++j){
          float v = acc[m][n][j] + bb;
          u16 hi = f2bf(v);
          u16 lo = f2bf(v - bf2f(hi));
          size_t base = ((size_t)(b * 16 + h) * 2048 + (size_t)(kb + j)) * 128;
          KS[base + d] = hi;
          KS[base + 64 + d] = lo;
        }
      }
    }
  } else {
    u16* VT = (u16*)C;   // [32][128][2048] u16 (aliases PROJ z==2 slice)
#pragma unroll
    for (int m = 0; m < 4; ++m){
      int r0 = by * 256 + wm * 64 + m * 16 + (lane >> 4) * 4;
      int b = r0 >> 11, kb = r0 & 2047;
#pragma unroll
      for (int n = 0; n < 4; ++n){
        int c = bx * 128 + wn * 64 + n * 16 + (lane & 15);
        float bb = bias[c];
        int h = c >> 6, d = c & 63;
        u16 hi[4], lo[4];
#pragma unroll
        for (int j = 0; j < 4; ++j){
          float v = acc[m][n][j] + bb;
          hi[j] = f2bf(v);
          lo[j] = f2bf(v - bf2f(hi[j]));
        }
        size_t base = ((size_t)(b * 16 + h) * 128) * 2048 + (size_t)kb;
        *reinterpret_cast<ushort4*>(&VT[base + (size_t)d * 2048]) =
            make_ushort4(hi[0], hi[1], hi[2], hi[3]);
        *reinterpret_cast<ushort4*>(&VT[base + (size_t)(64 + d) * 2048]) =
            make_ushort4(lo[0], lo[1], lo[2], lo[3]);
      }
    }
  }
}

// ---------- K4: q_norm coalesced: one token row (1024 f32) per 256 threads ----------
// also zeroes hmask (must run before topk)
__global__ __launch_bounds__(256) void qnorm_kernel(const float* __restrict__ PROJ,
                                                    float* __restrict__ qn,
                                                    unsigned int* __restrict__ hmask){
  int t = threadIdx.x;
  int gid = blockIdx.x * 256 + t;
  if (gid < 4096) hmask[gid] = 0;
  int h = t >> 4, q4 = t & 15;
#pragma unroll
  for (int it = 0; it < 8; ++it){
    int tok = blockIdx.x * 8 + it;          // b*2048 + l, 0..4095
    const float* row = PROJ + (size_t)tok * 1024;
    float4 x = *reinterpret_cast<const float4*>(&row[h * 64 + q4 * 4]);
    float s = x.x*x.x + x.y*x.y + x.z*x.z + x.w*x.w;
    s += __shfl_xor(s, 1);
    s += __shfl_xor(s, 2);
    s += __shfl_xor(s, 4);
    s += __shfl_xor(s, 8);
    if (q4 == 0){
      int b = tok >> 11, l = tok & 2047;
      qn[(size_t)(b * 16 + h) * 2048 + l] = s;
    }
  }
}

// ---------- K5: top-u argmax per (b,h); regs + shfl butterfly; tie -> lower idx ----------
__global__ __launch_bounds__(512) void topk_kernel(
    const float* __restrict__ qn, int* __restrict__ topk,
    unsigned char* __restrict__ seli, unsigned int* __restrict__ hmask,
    const int* __restrict__ qvlp){
  int bh = blockIdx.x; int b = bh >> 4, h = bh & 15;
  int u = compute_u(qvlp[0]);
  int t = threadIdx.x;                       // 512 threads, 4 values each
  float4 v4 = *reinterpret_cast<const float4*>(qn + (size_t)bh * 2048 + t * 4);
  float v[4] = {v4.x, v4.y, v4.z, v4.w};
  __shared__ float swv[8];
  __shared__ int swi[8];
  __shared__ int sidx;
  int lane = t & 63, w = t >> 6;
  for (int it = 0; it < u; ++it){
    float bv = v[0]; int bi = t * 4;
#pragma unroll
    for (int j = 1; j < 4; ++j){
      if (v[j] > bv){ bv = v[j]; bi = t * 4 + j; }      // strict >: keeps lower idx
    }
#pragma unroll
    for (int off = 1; off < 64; off <<= 1){
      float ov = __shfl_xor(bv, off);
      int   oi = __shfl_xor(bi, off);
      if (ov > bv || (ov == bv && oi < bi)){ bv = ov; bi = oi; }
    }
    if (lane == 0){ swv[w] = bv; swi[w] = bi; }
    __syncthreads();
    if (t == 0){
      float fv = swv[0]; int fi = swi[0];
#pragma unroll
      for (int k = 1; k < 8; ++k){
        if (swv[k] > fv || (swv[k] == fv && swi[k] < fi)){ fv = swv[k]; fi = swi[k]; }
      }
      sidx = fi;
      topk[bh * 64 + it] = fi;
      seli[(size_t)bh * 2048 + fi] = (unsigned char)it;
      atomicOr(&hmask[b * 2048 + fi], 1u << h);
    }
    __syncthreads();
    int idx = sidx;
    if ((idx >> 2) == t) v[idx & 3] = -3.4e38f;
  }
}

// ---------- K6a: gather selected Q rows -> split-bf16 QS[bh][64][128] (hi|lo) ----------
__global__ void qs_gather(const float* __restrict__ PROJ, const int* __restrict__ topk,
                          u16* __restrict__ QS, const int* __restrict__ qvlp){
  int bh = blockIdx.x; int b = bh >> 4, h = bh & 15;
  int u = compute_u(qvlp[0]);
  __shared__ int idx[64];
  int t = threadIdx.x;
  if (t < 64) idx[t] = (t < u) ? topk[bh * 64 + t] : 0;
  __syncthreads();
  for (int e = t; e < 64 * 64; e += 256){
    int i = e >> 6, d = e & 63;
    float v = 0.f;
    if (i < u) v = PROJ[(size_t)(b * 2048 + idx[i]) * 1024 + h * 64 + d];
    u16 hi = f2bf(v);
    u16 lo = f2bf(v - bf2f(hi));
    QS[(size_t)bh * 8192 + i * 128 + d] = hi;
    QS[(size_t)bh * 8192 + i * 128 + 64 + d] = lo;
  }
}

// ---------- K6b: scores via MFMA: S = Q_sel @ K^T, bf16 round + bf16 mask add ----------
// 4-term split product (hh,hl,lh,ll) ~ f32-accurate. Block: 64 q-rows x 128 keys.
__global__ __launch_bounds__(256) void scores_mfma(
    const u16* __restrict__ QS, const u16* __restrict__ KS,
    const int* __restrict__ topk, const float* __restrict__ maskp,
    u16* __restrict__ sc, const int* __restrict__ qvlp, const int* __restrict__ kvlp)
{
  int bh = blockIdx.y;
  int kvlv = kvlp[0]; if (kvlv > 2048) kvlv = 2048; if (kvlv < 0) kvlv = 0;
  int u = compute_u(qvlp[0]);
  int k0 = blockIdx.x * 128;
  if (k0 >= kvlv) return;
  int t = threadIdx.x, wave = t >> 6, lane = t & 63;
  int lr = lane & 15, lk = lane >> 4;
  __shared__ int idx_l[64];
  if (t < 64) idx_l[t] = (t < u) ? topk[bh * 64 + t] : 0;
  __syncthreads();
  const u16* Qb = QS + (size_t)bh * 8192;
  const u16* Kb = KS + (size_t)bh * 2048 * 128;
  // A frags: q-row = wave*16 + lr; k-window ks covers d = ks*32 + lk*8
  bf16x8 ah[2], al[2];
#pragma unroll
  for (int ks = 0; ks < 2; ++ks){
    const u16* qrow = &Qb[(wave * 16 + lr) * 128];
    ah[ks] = *reinterpret_cast<const bf16x8*>(&qrow[ks * 32 + lk * 8]);
    al[ks] = *reinterpret_cast<const bf16x8*>(&qrow[64 + ks * 32 + lk * 8]);
  }
  f32x4 acc[8] = {};
#pragma unroll
  for (int n = 0; n < 8; ++n){
    const u16* krow = &Kb[(size_t)(k0 + n * 16 + lr) * 128];
    bf16x8 bh0 = *reinterpret_cast<const bf16x8*>(&krow[lk * 8]);
    bf16x8 bh1 = *reinterpret_cast<const bf16x8*>(&krow[32 + lk * 8]);
    bf16x8 bl0 = *reinterpret_cast<const bf16x8*>(&krow[64 + lk * 8]);
    bf16x8 bl1 = *reinterpret_cast<const bf16x8*>(&krow[96 + lk * 8]);
    acc[n] = __builtin_amdgcn_mfma_f32_16x16x32_bf16(ah[0], bh0, acc[n], 0, 0, 0);
    acc[n] = __builtin_amdgcn_mfma_f32_16x16x32_bf16(ah[0], bl0, acc[n], 0, 0, 0);
    acc[n] = __builtin_amdgcn_mfma_f32_16x16x32_bf16(al[0], bh0, acc[n], 0, 0, 0);
    acc[n] = __builtin_amdgcn_mfma_f32_16x16x32_bf16(al[0], bl0, acc[n], 0, 0, 0);
    acc[n] = __builtin_amdgcn_mfma_f32_16x16x32_bf16(ah[1], bh1, acc[n], 0, 0, 0);
    acc[n] = __builtin_amdgcn_mfma_f32_16x16x32_bf16(ah[1], bl1, acc[n], 0, 0, 0);
    acc[n] = __builtin_amdgcn_mfma_f32_16x16x32_bf16(al[1], bh1, acc[n], 0, 0, 0);
    acc[n] = __builtin_amdgcn_mfma_f32_16x16x32_bf16(al[1], bl1, acc[n], 0, 0, 0);
  }
  // epilogue: C col = lane&15 (key), row = (lane>>4)*4 + j (q within wave's 16)
#pragma unroll
  for (int n = 0; n < 8; ++n){
    int k = k0 + n * 16 + lr;
    if (k >= kvlv) continue;
#pragma unroll
    for (int j = 0; j < 4; ++j){
      int i = wave * 16 + lk * 4 + j;
      if (i >= u) continue;
      float s = acc[n][j] * 0.125f;               // / sqrt(64)
      u16 xb = f2bf(s);                           // scores.astype(bf16)
      u16 mb = f2bf(maskp[(size_t)idx_l[i] * 2048 + k]);  // attn_mask.astype(bf16)
      u16 xm = f2bf(bf2f(xb) + bf2f(mb));         // bf16 add
      sc[(size_t)(bh * 64 + i) * 2048 + k] = xm;
    }
  }
}

// ---------- K7: exact bf16 softmax emulation; p written in place ----------
__global__ void softmax_kernel(u16* __restrict__ sc, const int* __restrict__ qvlp,
                               const int* __restrict__ kvlp){
  int bh = blockIdx.y, i = blockIdx.x;
  int u = compute_u(qvlp[0]);
  if (i >= u) return;
  int kvlv = kvlp[0]; if (kvlv > 2048) kvlv = 2048; if (kvlv < 0) kvlv = 0;
  u16* row = sc + (size_t)(bh * 64 + i) * 2048;
  int t = threadIdx.x;
  float x[8];
  float lm = -3.4e38f;
#pragma unroll
  for (int j = 0; j < 8; ++j){
    int k = t + j * 256;
    x[j] = (k < kvlv) ? bf2f(row[k]) : -3.4e38f;
    lm = fmaxf(lm, x[j]);
  }
  __shared__ float red[256];
  red[t] = lm; __syncthreads();
  for (int s = 128; s > 0; s >>= 1){ if (t < s) red[t] = fmaxf(red[t], red[t+s]); __syncthreads(); }
  float m = red[0];
  __syncthreads();
  float e[8]; float ls = 0.f;
#pragma unroll
  for (int j = 0; j < 8; ++j){
    int k = t + j * 256;
    if (k < kvlv){
      u16 ub = f2bf(x[j] - m);            // bf16 subtract
      u16 eb = f2bf(expf(bf2f(ub)));      // bf16 exp
      e[j] = bf2f(eb);
      ls += e[j];
    } else e[j] = 0.f;
  }
  red[t] = ls; __syncthreads();
  for (int s = 128; s > 0; s >>= 1){ if (t < s) red[t] += red[t+s]; __syncthreads(); }
  float S = red[0];                       // f32 accumulation (jnp.sum upcast)
  float Sb = bf2f(f2bf(S));               // downcast back to bf16
#pragma unroll
  for (int j = 0; j < 8; ++j){
    int k = t + j * 256;
    if (k < 2048) row[k] = (k < kvlv) ? f2bf(e[j] / Sb) : (u16)0;   // bf16 divide
  }
}

// ---------- K8a: PV via MFMA, no LDS. part[kc][bh][64 rows][64 d] ----------
__global__ void pv_mfma(const u16* __restrict__ probs, const u16* __restrict__ VT,
                        float* __restrict__ part, const int* __restrict__ kvlp)
{
  int bh = blockIdx.y; int b = bh >> 4, h = bh & 15;
  int kvlv = kvlp[0]; if (kvlv > 2048) kvlv = 2048; if (kvlv < 0) kvlv = 0;
  int kc = blockIdx.x;
  int k0 = kc * 128;
  if (k0 >= kvlv) return;
  int t = threadIdx.x, w = t >> 6, lane = t & 63;
  int lr = lane & 15, lk = lane >> 4;
  const u16* Pb = probs + (size_t)bh * 64 * 2048;
  const u16* Vb = VT + (size_t)(b * 16 + h) * 128 * 2048;
  f32x4 acc[4] = {};
#pragma unroll
  for (int ks = 0; ks < 4; ++ks){
    int kk = k0 + ks * 32 + lk * 8;
    bf16x8 A0 = *reinterpret_cast<const bf16x8*>(Pb + (size_t)(lr     ) * 2048 + kk);
    bf16x8 A1 = *reinterpret_cast<const bf16x8*>(Pb + (size_t)(lr + 16) * 2048 + kk);
    bf16x8 A2 = *reinterpret_cast<const bf16x8*>(Pb + (size_t)(lr + 32) * 2048 + kk);
    bf16x8 A3 = *reinterpret_cast<const bf16x8*>(Pb + (size_t)(lr + 48) * 2048 + kk);
    bf16x8 Bh = *reinterpret_cast<const bf16x8*>(Vb + (size_t)(w * 16 + lr     ) * 2048 + kk);
    bf16x8 Bl = *reinterpret_cast<const bf16x8*>(Vb + (size_t)(w * 16 + lr + 64) * 2048 + kk);
    acc[0] = __builtin_amdgcn_mfma_f32_16x16x32_bf16(A0, Bh, acc[0], 0, 0, 0);
    acc[1] = __builtin_amdgcn_mfma_f32_16x16x32_bf16(A1, Bh, acc[1], 0, 0, 0);
    acc[2] = __builtin_amdgcn_mfma_f32_16x16x32_bf16(A2, Bh, acc[2], 0, 0, 0);
    acc[3] = __builtin_amdgcn_mfma_f32_16x16x32_bf16(A3, Bh, acc[3], 0, 0, 0);
    acc[0] = __builtin_amdgcn_mfma_f32_16x16x32_bf16(A0, Bl, acc[0], 0, 0, 0);
    acc[1] = __builtin_amdgcn_mfma_f32_16x16x32_bf16(A1, Bl, acc[1], 0, 0, 0);
    acc[2] = __builtin_amdgcn_mfma_f32_16x16x32_bf16(A2, Bl, acc[2], 0, 0, 0);
    acc[3] = __builtin_amdgcn_mfma_f32_16x16x32_bf16(A3, Bl, acc[3], 0, 0, 0);
  }
  float* pc = part + (size_t)(kc * 32 + bh) * 64 * 64;
#pragma unroll
  for (int m = 0; m < 4; ++m){
    int row = m * 16 + lk * 4;
#pragma unroll
    for (int j = 0; j < 4; ++j)
      pc[(size_t)(row + j) * 64 + w * 16 + lr] = acc[m][j];
  }
}

// ---------- K8b: deterministic reduction of PV partials ----------
__global__ void pv_reduce(const float* __restrict__ part, float* __restrict__ ctx,
                          const int* __restrict__ qvlp, const int* __restrict__ kvlp){
  int bh = blockIdx.y, r = blockIdx.x;
  int u = compute_u(qvlp[0]);
  if (r >= u) return;
  int kvlv = kvlp[0]; if (kvlv > 2048) kvlv = 2048; if (kvlv < 0) kvlv = 0;
  int kcmax = (kvlv + 127) / 128;
  int d = threadIdx.x;   // 64
  float s = 0.f;
  for (int kc = 0; kc < kcmax; ++kc)
    s += part[(size_t)((kc * 32 + bh) * 64 + r) * 64 + d];
  ctx[(size_t)(bh * 64 + r) * 64 + d] = s;
}

// ---------- K9: sparse output projection; unselected rows = bo ----------
__global__ void outproj_kernel(const float* __restrict__ ctx, const float* __restrict__ WoT,
                               const float* __restrict__ bo, const unsigned int* __restrict__ hmask,
                               const unsigned char* __restrict__ seli, float* __restrict__ out){
  int row = blockIdx.x;                 // b*2048 + l
  int b = row >> 11, l = row & 2047;
  int t = threadIdx.x;
  float acc[4];
#pragma unroll
  for (int r = 0; r < 4; ++r) acc[r] = bo[t + r * 256];
  unsigned int m = hmask[row];
  __shared__ float clds[64];
  while (m){
    int h = __ffs(m) - 1; m &= (m - 1);
    int i = (int)seli[(size_t)(b * 16 + h) * 2048 + l];
    __syncthreads();
    if (t < 64) clds[t] = ctx[(size_t)((b * 16 + h) * 64 + i) * 64 + t];
    __syncthreads();
    for (int j = 0; j < 64; ++j){
      float c = clds[j];
      const float* wrow = &WoT[(size_t)(h * 64 + j) * 1024];
#pragma unroll
      for (int r = 0; r < 4; ++r) acc[r] += c * wrow[t + r * 256];
    }
  }
  float* orow = out + (size_t)row * 1024;
#pragma unroll
  for (int r = 0; r < 4; ++r) orow[t + r * 256] = acc[r];
}

__global__ void fail_fill(float* o, int n){
  int i = blockIdx.x * 256 + threadIdx.x;
  if (i < n) o[i] = 12345.0f;
}

// ---------------------------------------------------------------------------
extern "C" void kernel_launch(void* const* d_in, const int* in_sizes, int n_in,
                              void* d_out, int out_size, void* d_ws, size_t ws_size,
                              hipStream_t stream)
{
  const float* query = (const float*)d_in[0];
  const float* key   = (const float*)d_in[1];
  const float* value = (const float*)d_in[2];
  const float* maskp = (const float*)d_in[3];
  const float* Wq = (const float*)d_in[4];
  const float* bq = (const float*)d_in[5];
  const float* Wk = (const float*)d_in[6];
  const float* bk = (const float*)d_in[7];
  const float* Wv = (const float*)d_in[8];
  const float* bv = (const float*)d_in[9];
  const float* Wo = (const float*)d_in[10];
  const float* bo = (const float*)d_in[11];
  const int* qvl = (const int*)d_in[12];
  const int* kvl = (const int*)d_in[13];
  float* out = (float*)d_out;

  char* ws = (char*)d_ws;
  size_t off = 0;
  auto alloc = [&](size_t bytes) -> void* {
    void* p = ws + off;
    off = (off + bytes + 255) & ~(size_t)255;
    return p;
  };
  u16* X1 = (u16*)alloc(3ull * 4194304 * 2);
  u16* X2 = (u16*)alloc(3ull * 4194304 * 2);
  u16* X3 = (u16*)alloc(1ull * 4194304 * 2);
  u16* W1 = (u16*)alloc(3ull * 1048576 * 2);
  u16* W2 = (u16*)alloc(3ull * 1048576 * 2);
  u16* W3 = (u16*)alloc(1ull * 1048576 * 2);
  float* PROJ = (float*)alloc(3ull * 4194304 * 4);
  float* WOT  = (float*)alloc(4194304ull);
  float* QN   = (float*)alloc(2ull * 16 * 2048 * 4);
  int*   TOPK = (int*)alloc(2ull * 16 * 64 * 4);
  unsigned char* SELI = (unsigned char*)alloc(2ull * 16 * 2048);
  unsigned int* HMASK = (unsigned int*)alloc(2ull * 2048 * 4);
  u16*   SC   = (u16*)alloc(2048ull * 2048 * 2);
  float* CTX  = (float*)alloc(2048ull * 64 * 4);
  u16*   QS   = (u16*)alloc(32ull * 64 * 128 * 2);

  // KS (split-bf16 K) aliases the PROJ z==1 slice (exactly 16.78 MB)
  u16* KS = (u16*)(PROJ + 1ull * 4194304);
  // VT (split-bf16 transposed V) aliases the PROJ z==2 slice (exactly 16.78 MB)
  u16* VT = (u16*)(PROJ + 2ull * 4194304);
  // PV partials alias X1 (24 MB, dead after gemm_proj): 16*32*64*64*4 = 8.4 MB
  float* PART = (float*)X1;

  if (ws_size < off){
    fail_fill<<<(out_size + 255) / 256, 256, 0, stream>>>(out, out_size);
    return;
  }

  expand_kernel<<<15360, 256, 0, stream>>>(query, key, value, Wq, Wk, Wv,
                                           X1, X2, X3, W1, W2, W3);
  wot_kernel<<<dim3(32, 32), dim3(32, 8), 0, stream>>>(Wo, WOT);
  gemm_proj<<<dim3(8, 16, 3), 512, 0, stream>>>(X1, X2, X3, W1, W2, W3, bq, bk, bv, PROJ);
  qnorm_kernel<<<512, 256, 0, stream>>>(PROJ, QN, HMASK);
  topk_kernel<<<32, 512, 0, stream>>>(QN, TOPK, SELI, HMASK, qvl);
  qs_gather<<<32, 256, 0, stream>>>(PROJ, TOPK, QS, qvl);
  scores_mfma<<<dim3(16, 32), 256, 0, stream>>>(QS, KS, TOPK, maskp, SC, qvl, kvl);
  softmax_kernel<<<dim3(64, 32), 256, 0, stream>>>(SC, qvl, kvl);
  pv_mfma<<<dim3(16, 32), 256, 0, stream>>>(SC, VT, PART, kvl);
  pv_reduce<<<dim3(64, 32), 64, 0, stream>>>(PART, CTX, qvl, kvl);
  outproj_kernel<<<4096, 256, 0, stream>>>(CTX, WOT, bo, HMASK, SELI, out);
}